// Round 2
// baseline (3212.670 us; speedup 1.0000x reference)
//
#include <hip/hip_runtime.h>
#include <hip/hip_bf16.h>

// Problem constants
#define B_     8
#define N_     1024
#define DIM_   512
#define H_     8
#define HD_    64
#define INNER_ 512
#define QKVC   2048   // 4*INNER
#define M_     8192   // B*N

// ---------------------------------------------------------------------------
// Tiled GEMM: C[M,N] = A[M,K] @ B[K,N] (+ bias). All f32.
// 128x128 tile, BK=16, 256 thr, 8x8/thr.
// ---------------------------------------------------------------------------
template<bool BIAS>
__global__ __launch_bounds__(256)
void gemm_kernel(const float* __restrict__ Ap, const float* __restrict__ Bw,
                 const float* __restrict__ bias, float* __restrict__ Cp,
                 int M, int N, int K)
{
    __shared__ float sA[16][128];
    __shared__ float sB[16][128];
    const int t  = threadIdx.x;
    const int tx = t & 15, ty = t >> 4;
    const int m0 = blockIdx.y * 128, n0 = blockIdx.x * 128;

    float acc[8][8];
#pragma unroll
    for (int i = 0; i < 8; i++)
#pragma unroll
        for (int j = 0; j < 8; j++) acc[i][j] = 0.f;

    const int ar = t >> 1;          // 0..127 : A row in tile
    const int ak = (t & 1) * 8;     // 0 or 8 : A k-offset
    const int bk = t >> 4;          // 0..15  : B row in tile
    const int bc = (t & 15) * 8;    // B col offset

    for (int k0 = 0; k0 < K; k0 += 16) {
        {
            const float* ap = Ap + (size_t)(m0 + ar) * K + k0 + ak;
            float4 a0 = *(const float4*)ap;
            float4 a1 = *((const float4*)ap + 1);
            sA[ak + 0][ar] = a0.x; sA[ak + 1][ar] = a0.y;
            sA[ak + 2][ar] = a0.z; sA[ak + 3][ar] = a0.w;
            sA[ak + 4][ar] = a1.x; sA[ak + 5][ar] = a1.y;
            sA[ak + 6][ar] = a1.z; sA[ak + 7][ar] = a1.w;
        }
        {
            const float* bp = Bw + (size_t)(k0 + bk) * N + n0 + bc;
            float4 b0 = *(const float4*)bp;
            float4 b1 = *((const float4*)bp + 1);
            sB[bk][bc + 0] = b0.x; sB[bk][bc + 1] = b0.y;
            sB[bk][bc + 2] = b0.z; sB[bk][bc + 3] = b0.w;
            sB[bk][bc + 4] = b1.x; sB[bk][bc + 5] = b1.y;
            sB[bk][bc + 6] = b1.z; sB[bk][bc + 7] = b1.w;
        }
        __syncthreads();
#pragma unroll
        for (int kk = 0; kk < 16; kk++) {
            float a[8], b[8];
            float4 t0 = *(const float4*)&sA[kk][ty * 4];
            float4 t1 = *(const float4*)&sA[kk][64 + ty * 4];
            a[0] = t0.x; a[1] = t0.y; a[2] = t0.z; a[3] = t0.w;
            a[4] = t1.x; a[5] = t1.y; a[6] = t1.z; a[7] = t1.w;
            float4 s0 = *(const float4*)&sB[kk][tx * 4];
            float4 s1 = *(const float4*)&sB[kk][64 + tx * 4];
            b[0] = s0.x; b[1] = s0.y; b[2] = s0.z; b[3] = s0.w;
            b[4] = s1.x; b[5] = s1.y; b[6] = s1.z; b[7] = s1.w;
#pragma unroll
            for (int i = 0; i < 8; i++)
#pragma unroll
                for (int j = 0; j < 8; j++) acc[i][j] += a[i] * b[j];
        }
        __syncthreads();
    }

    float bv[8];
#pragma unroll
    for (int j = 0; j < 8; j++) {
        int col = n0 + ((j < 4) ? tx * 4 + j : 64 + tx * 4 + (j - 4));
        bv[j] = BIAS ? bias[col] : 0.f;
    }
#pragma unroll
    for (int i = 0; i < 8; i++) {
        int row = m0 + ((i < 4) ? ty * 4 + i : 64 + ty * 4 + (i - 4));
#pragma unroll
        for (int j = 0; j < 8; j++) {
            int col = n0 + ((j < 4) ? tx * 4 + j : 64 + tx * 4 + (j - 4));
            Cp[(size_t)row * N + col] = acc[i][j] + bv[j];
        }
    }
}

// ---------------------------------------------------------------------------
// Depthwise conv (k=5, pad=2) over feature axis + sigmoid gate.
// One block per (b,n) row: MS = s1+s2 (f32 in qkv ws), A = conv(MS)+cb,
// MSg = sigmoid(A)*MS.
// ---------------------------------------------------------------------------
__global__ __launch_bounds__(128)
void convgate_kernel(const float* __restrict__ qkv1, const float* __restrict__ qkv2,
                     const float* __restrict__ convw,
                     const float* __restrict__ convb,
                     float* __restrict__ MSg)
{
    __shared__ float ms[INNER_];
    const int blk = blockIdx.x;            // b*N + n
    const int n = blk & (N_ - 1);
    const int t = threadIdx.x;             // 0..127, 4 features each

    const float4* q1 = (const float4*)(qkv1 + (size_t)blk * QKVC + 3 * INNER_);
    const float4* q2 = (const float4*)(qkv2 + (size_t)blk * QKVC + 3 * INNER_);
    float4 v1 = q1[t], v2 = q2[t];
    float4 s;
    s.x = v1.x + v2.x; s.y = v1.y + v2.y; s.z = v1.z + v2.z; s.w = v1.w + v2.w;
    *(float4*)&ms[t * 4] = s;
    __syncthreads();

    float w[5];
#pragma unroll
    for (int k = 0; k < 5; k++) w[k] = convw[n * 5 + k];
    const float cb = convb[n];

    float out[4];
#pragma unroll
    for (int ff = 0; ff < 4; ff++) {
        int f = t * 4 + ff;
        float A = cb;
#pragma unroll
        for (int k = 0; k < 5; k++) {
            int idx = f + k - 2;
            if (idx >= 0 && idx < INNER_) A += ms[idx] * w[k];
        }
        float sg = 1.f / (1.f + __expf(-A));
        out[ff] = ms[f] * sg;
    }
    *(float4*)&MSg[(size_t)blk * INNER_ + t * 4] = make_float4(out[0], out[1], out[2], out[3]);
}

// ---------------------------------------------------------------------------
// Generic attention: O = softmax(Q K^T * scale) @ V (+V residual). NV=2 shares
// the score matrix across two V/O pairs. Per-(b,h) addressing via (sb,sh,sr).
// Block: 256 thr, TI=8 query rows, full 1024-wide score row in LDS.
// ---------------------------------------------------------------------------
#define TI  8
#define TJ  32
#define KVP 68     // kv tile pitch (floats), 17*16B -> float4-aligned rows
#define SSP 1025   // score row pitch

template<int NV, bool RESID>
__global__ __launch_bounds__(256)
void attn_kernel(const float* __restrict__ Qb, long long q_sb, long long q_sh, int q_sr,
                 const float* __restrict__ Kb, long long k_sb, long long k_sh, int k_sr,
                 const float* __restrict__ V0b, const float* __restrict__ V1b,
                 long long v_sb, long long v_sh, int v_sr,
                 float* __restrict__ O0b, float* __restrict__ O1b,
                 long long o_sb, long long o_sh, int o_sr)
{
    __shared__ float qs[TI][64];
    __shared__ float kv0[TJ][KVP];
    __shared__ float kv1[(NV == 2) ? TJ : 1][KVP];
    __shared__ float ss[TI][SSP];
    __shared__ float red[TI][33];
    __shared__ float rowmax[TI], rowinv[TI];

    const int t = threadIdx.x;
    const int bh = blockIdx.y;
    const int b = bh >> 3, h = bh & 7;
    const int i0 = blockIdx.x * TI;

    const float* Q  = Qb  + (size_t)b * q_sb + (size_t)h * q_sh;
    const float* Kg = Kb  + (size_t)b * k_sb + (size_t)h * k_sh;
    const float* V0 = V0b + (size_t)b * v_sb + (size_t)h * v_sh;
    const float* V1 = (NV == 2) ? (V1b + (size_t)b * v_sb + (size_t)h * v_sh) : nullptr;
    float* O0 = O0b + (size_t)b * o_sb + (size_t)h * o_sh;
    float* O1 = (NV == 2) ? (O1b + (size_t)b * o_sb + (size_t)h * o_sh) : nullptr;

    // Q tile: 8 rows x 64 = 128 float4
    if (t < 128) {
        int row = t >> 4, d4 = t & 15;
        *(float4*)&qs[row][d4 * 4] = *(const float4*)(Q + (size_t)(i0 + row) * q_sr + d4 * 4);
    }
    __syncthreads();

    const float scale = 0.125f;

    // Phase 1: scores -> ss
    {
        const int j = t & 31;      // j within tile
        const int i = t >> 5;      // 0..7
        for (int j0 = 0; j0 < N_; j0 += TJ) {
#pragma unroll
            for (int p = 0; p < 2; p++) {
                int f = t + p * 256;           // float4 index 0..511
                int row = f >> 4, d4 = f & 15;
                *(float4*)&kv0[row][d4 * 4] =
                    *(const float4*)(Kg + (size_t)(j0 + row) * k_sr + d4 * 4);
            }
            __syncthreads();
            float dot = 0.f;
#pragma unroll
            for (int d4 = 0; d4 < 16; d4++) {
                float4 kv = *(const float4*)&kv0[j][d4 * 4];
                float4 qv = *(const float4*)&qs[i][d4 * 4];
                dot += kv.x * qv.x + kv.y * qv.y + kv.z * qv.z + kv.w * qv.w;
            }
            ss[i][j0 + j] = dot * scale;
            __syncthreads();
        }
    }

    // Phase 2: row softmax stats (keep exp() in ss, normalize at the end)
    {
        const int r = t >> 5, c = t & 31;
        float m = -1e30f;
        for (int e = 0; e < 32; e++) m = fmaxf(m, ss[r][c + 32 * e]);
        red[r][c] = m;
        __syncthreads();
        if (t < TI) {
            float mm = red[t][0];
            for (int e = 1; e < 32; e++) mm = fmaxf(mm, red[t][e]);
            rowmax[t] = mm;
        }
        __syncthreads();
        float rm = rowmax[r];
        float sum = 0.f;
        for (int e = 0; e < 32; e++) {
            int idx = c + 32 * e;
            float v = __expf(ss[r][idx] - rm);
            ss[r][idx] = v;
            sum += v;
        }
        red[r][c] = sum;
        __syncthreads();
        if (t < TI) {
            float s2 = 0.f;
            for (int e = 0; e < 32; e++) s2 += red[t][e];
            rowinv[t] = 1.0f / s2;
        }
        __syncthreads();
    }

    // Phase 3: apply to V (and V1)
    {
        const int i = t >> 5;      // 0..7
        const int c = t & 31;      // d = c*2
        float2 acc0 = {0.f, 0.f}, acc1 = {0.f, 0.f};
        for (int j0 = 0; j0 < N_; j0 += TJ) {
#pragma unroll
            for (int p = 0; p < 2; p++) {
                int f = t + p * 256;
                int row = f >> 4, d4 = f & 15;
                *(float4*)&kv0[row][d4 * 4] =
                    *(const float4*)(V0 + (size_t)(j0 + row) * v_sr + d4 * 4);
                if constexpr (NV == 2)
                    *(float4*)&kv1[row][d4 * 4] =
                        *(const float4*)(V1 + (size_t)(j0 + row) * v_sr + d4 * 4);
            }
            __syncthreads();
#pragma unroll 8
            for (int jj = 0; jj < TJ; jj++) {
                float p_ = ss[i][j0 + jj];
                float2 v0 = *(const float2*)&kv0[jj][c * 2];
                acc0.x += p_ * v0.x; acc0.y += p_ * v0.y;
                if constexpr (NV == 2) {
                    float2 vv = *(const float2*)&kv1[jj][c * 2];
                    acc1.x += p_ * vv.x; acc1.y += p_ * vv.y;
                }
            }
            __syncthreads();
        }
        float inv = rowinv[i];
        acc0.x *= inv; acc0.y *= inv;
        if constexpr (RESID) {
            float2 r0 = *(const float2*)(V0 + (size_t)(i0 + i) * v_sr + c * 2);
            acc0.x += r0.x; acc0.y += r0.y;
        }
        *(float2*)(O0 + (size_t)(i0 + i) * o_sr + c * 2) = acc0;
        if constexpr (NV == 2) {
            acc1.x *= inv; acc1.y *= inv;
            if constexpr (RESID) {
                float2 r1 = *(const float2*)(V1 + (size_t)(i0 + i) * v_sr + c * 2);
                acc1.x += r1.x; acc1.y += r1.y;
            }
            *(float2*)(O1 + (size_t)(i0 + i) * o_sr + c * 2) = acc1;
        }
    }
}

// ---------------------------------------------------------------------------
extern "C" void kernel_launch(void* const* d_in, const int* in_sizes, int n_in,
                              void* d_out, int out_size, void* d_ws, size_t ws_size,
                              hipStream_t stream)
{
    const float* x1    = (const float*)d_in[0];
    const float* x2    = (const float*)d_in[1];
    const float* Wqkv1 = (const float*)d_in[2];
    const float* Wqkv2 = (const float*)d_in[3];
    const float* Wout1 = (const float*)d_in[4];
    const float* bout1 = (const float*)d_in[5];
    const float* Wout2 = (const float*)d_in[6];
    const float* bout2 = (const float*)d_in[7];
    const float* convw = (const float*)d_in[8];
    const float* convb = (const float*)d_in[9];

    // Workspace layout (f32): qkv1(32M) qkv2(32M) MSg u1 u2 t1m t2m (4M each)
    const size_t QKV_ELEMS = (size_t)M_ * QKVC;       // 16,777,216
    const size_t BND_ELEMS = (size_t)M_ * INNER_;     //  4,194,304
    if (ws_size < (2 * QKV_ELEMS + 5 * BND_ELEMS) * sizeof(float)) return;

    float* ws   = (float*)d_ws;
    float* qkv1 = ws;
    float* qkv2 = qkv1 + QKV_ELEMS;
    float* MSg  = qkv2 + QKV_ELEMS;
    float* u1   = MSg + BND_ELEMS;
    float* u2   = u1 + BND_ELEMS;
    float* t1m  = u2 + BND_ELEMS;
    float* t2m  = t1m + BND_ELEMS;

    dim3 blk(256);

    // 1) QKV projections
    gemm_kernel<false><<<dim3(QKVC / 128, M_ / 128), blk, 0, stream>>>(
        x1, Wqkv1, nullptr, qkv1, M_, QKVC, DIM_);
    gemm_kernel<false><<<dim3(QKVC / 128, M_ / 128), blk, 0, stream>>>(
        x2, Wqkv2, nullptr, qkv2, M_, QKVC, DIM_);

    // 2) conv + sigmoid gate -> MSg
    convgate_kernel<<<dim3(M_), dim3(128), 0, stream>>>(qkv1, qkv2, convw, convb, MSg);

    // Stride descriptors
    const long long msg_sb = (long long)N_ * INNER_, msg_sh = HD_;
    const int       msg_sr = INNER_;
    const long long qkv_sb = (long long)N_ * QKVC, qkv_sh = HD_;
    const int       qkv_sr = QKVC;
    const long long u_sb = (long long)H_ * N_ * HD_, u_sh = (long long)N_ * HD_;
    const int       u_sr = HD_;

    // 3) Attention A: scores from MSg heads, apply to v1 & v2 with +v residual
    attn_kernel<2, true><<<dim3(N_ / TI, B_ * H_), blk, 0, stream>>>(
        MSg, msg_sb, msg_sh, msg_sr,
        MSg, msg_sb, msg_sh, msg_sr,
        qkv1 + 2 * INNER_, qkv2 + 2 * INNER_, qkv_sb, qkv_sh, qkv_sr,
        u1, u2, u_sb, u_sh, u_sr);

    // 4) Attention B (stream 1 and 2): t = softmax(q k^T) @ u, merged-head out
    attn_kernel<1, false><<<dim3(N_ / TI, B_ * H_), blk, 0, stream>>>(
        qkv1, qkv_sb, qkv_sh, qkv_sr,
        qkv1 + INNER_, qkv_sb, qkv_sh, qkv_sr,
        u1, nullptr, u_sb, u_sh, u_sr,
        t1m, nullptr, msg_sb, msg_sh, msg_sr);
    attn_kernel<1, false><<<dim3(N_ / TI, B_ * H_), blk, 0, stream>>>(
        qkv2, qkv_sb, qkv_sh, qkv_sr,
        qkv2 + INNER_, qkv_sb, qkv_sh, qkv_sr,
        u2, nullptr, u_sb, u_sh, u_sr,
        t2m, nullptr, msg_sb, msg_sh, msg_sr);

    // 5) Output projections (bias, f32 out)
    float* out1 = (float*)d_out;
    float* out2 = out1 + (size_t)M_ * DIM_;
    gemm_kernel<true><<<dim3(DIM_ / 128, M_ / 128), blk, 0, stream>>>(
        t1m, Wout1, bout1, out1, M_, DIM_, DIM_);
    gemm_kernel<true><<<dim3(DIM_ / 128, M_ / 128), blk, 0, stream>>>(
        t2m, Wout2, bout2, out2, M_, DIM_, DIM_);
}

// Round 3
// 1659.084 us; speedup vs baseline: 1.9364x; 1.9364x over previous
//
#include <hip/hip_runtime.h>
#include <hip/hip_bf16.h>

// Problem constants
#define B_     8
#define N_     1024
#define DIM_   512
#define H_     8
#define HD_    64
#define INNER_ 512
#define QKVC   2048   // 4*INNER
#define M_     8192   // B*N

// ---------------------------------------------------------------------------
// Tiled GEMM: C[M,N] = A[M,K] @ B[K,N] (+ bias). All f32.
// 128x128 tile, BK=16, 256 thr, 8x8/thr.
// ---------------------------------------------------------------------------
template<bool BIAS>
__global__ __launch_bounds__(256)
void gemm_kernel(const float* __restrict__ Ap, const float* __restrict__ Bw,
                 const float* __restrict__ bias, float* __restrict__ Cp,
                 int M, int N, int K)
{
    __shared__ float sA[16][128];
    __shared__ float sB[16][128];
    const int t  = threadIdx.x;
    const int tx = t & 15, ty = t >> 4;
    const int m0 = blockIdx.y * 128, n0 = blockIdx.x * 128;

    float acc[8][8];
#pragma unroll
    for (int i = 0; i < 8; i++)
#pragma unroll
        for (int j = 0; j < 8; j++) acc[i][j] = 0.f;

    const int ar = t >> 1;          // 0..127 : A row in tile
    const int ak = (t & 1) * 8;     // 0 or 8 : A k-offset
    const int bk = t >> 4;          // 0..15  : B row in tile
    const int bc = (t & 15) * 8;    // B col offset

    for (int k0 = 0; k0 < K; k0 += 16) {
        {
            const float* ap = Ap + (size_t)(m0 + ar) * K + k0 + ak;
            float4 a0 = *(const float4*)ap;
            float4 a1 = *((const float4*)ap + 1);
            sA[ak + 0][ar] = a0.x; sA[ak + 1][ar] = a0.y;
            sA[ak + 2][ar] = a0.z; sA[ak + 3][ar] = a0.w;
            sA[ak + 4][ar] = a1.x; sA[ak + 5][ar] = a1.y;
            sA[ak + 6][ar] = a1.z; sA[ak + 7][ar] = a1.w;
        }
        {
            const float* bp = Bw + (size_t)(k0 + bk) * N + n0 + bc;
            float4 b0 = *(const float4*)bp;
            float4 b1 = *((const float4*)bp + 1);
            sB[bk][bc + 0] = b0.x; sB[bk][bc + 1] = b0.y;
            sB[bk][bc + 2] = b0.z; sB[bk][bc + 3] = b0.w;
            sB[bk][bc + 4] = b1.x; sB[bk][bc + 5] = b1.y;
            sB[bk][bc + 6] = b1.z; sB[bk][bc + 7] = b1.w;
        }
        __syncthreads();
#pragma unroll
        for (int kk = 0; kk < 16; kk++) {
            float a[8], b[8];
            float4 t0 = *(const float4*)&sA[kk][ty * 4];
            float4 t1 = *(const float4*)&sA[kk][64 + ty * 4];
            a[0] = t0.x; a[1] = t0.y; a[2] = t0.z; a[3] = t0.w;
            a[4] = t1.x; a[5] = t1.y; a[6] = t1.z; a[7] = t1.w;
            float4 s0 = *(const float4*)&sB[kk][tx * 4];
            float4 s1 = *(const float4*)&sB[kk][64 + tx * 4];
            b[0] = s0.x; b[1] = s0.y; b[2] = s0.z; b[3] = s0.w;
            b[4] = s1.x; b[5] = s1.y; b[6] = s1.z; b[7] = s1.w;
#pragma unroll
            for (int i = 0; i < 8; i++)
#pragma unroll
                for (int j = 0; j < 8; j++) acc[i][j] += a[i] * b[j];
        }
        __syncthreads();
    }

    float bv[8];
#pragma unroll
    for (int j = 0; j < 8; j++) {
        int col = n0 + ((j < 4) ? tx * 4 + j : 64 + tx * 4 + (j - 4));
        bv[j] = BIAS ? bias[col] : 0.f;
    }
#pragma unroll
    for (int i = 0; i < 8; i++) {
        int row = m0 + ((i < 4) ? ty * 4 + i : 64 + ty * 4 + (i - 4));
#pragma unroll
        for (int j = 0; j < 8; j++) {
            int col = n0 + ((j < 4) ? tx * 4 + j : 64 + tx * 4 + (j - 4));
            Cp[(size_t)row * N + col] = acc[i][j] + bv[j];
        }
    }
}

// ---------------------------------------------------------------------------
// Depthwise conv (k=5, pad=2) over feature axis + sigmoid gate.
// ---------------------------------------------------------------------------
__global__ __launch_bounds__(128)
void convgate_kernel(const float* __restrict__ qkv1, const float* __restrict__ qkv2,
                     const float* __restrict__ convw,
                     const float* __restrict__ convb,
                     float* __restrict__ MSg)
{
    __shared__ float ms[INNER_];
    const int blk = blockIdx.x;            // b*N + n
    const int n = blk & (N_ - 1);
    const int t = threadIdx.x;             // 0..127, 4 features each

    const float4* q1 = (const float4*)(qkv1 + (size_t)blk * QKVC + 3 * INNER_);
    const float4* q2 = (const float4*)(qkv2 + (size_t)blk * QKVC + 3 * INNER_);
    float4 v1 = q1[t], v2 = q2[t];
    float4 s;
    s.x = v1.x + v2.x; s.y = v1.y + v2.y; s.z = v1.z + v2.z; s.w = v1.w + v2.w;
    *(float4*)&ms[t * 4] = s;
    __syncthreads();

    float w[5];
#pragma unroll
    for (int k = 0; k < 5; k++) w[k] = convw[n * 5 + k];
    const float cb = convb[n];

    float out[4];
#pragma unroll
    for (int ff = 0; ff < 4; ff++) {
        int f = t * 4 + ff;
        float A = cb;
#pragma unroll
        for (int k = 0; k < 5; k++) {
            int idx = f + k - 2;
            if (idx >= 0 && idx < INNER_) A += ms[idx] * w[k];
        }
        float sg = 1.f / (1.f + __expf(-A));
        out[ff] = ms[f] * sg;
    }
    *(float4*)&MSg[(size_t)blk * INNER_ + t * 4] = make_float4(out[0], out[1], out[2], out[3]);
}

// ---------------------------------------------------------------------------
// Flash-style attention: O = softmax(Q K^T * scale) @ V (+V residual), f32.
// One block = one (b,h) x 64 query rows. j-tiles of 64 keys, online softmax.
// 256 thr as 16x16; thread (ty,tx) owns S[ty+16a][tx+16b], a,b=0..3 (stride-16
// scatter keeps every LDS read <=2-way / broadcast). P goes through LDS
// (aliased over the K buffer). O accum in registers, cols tx*4..+3.
// NV=2 shares P with two V/O pairs (scores computed once).
// ---------------------------------------------------------------------------
#define FP 68   // LDS row pitch (floats), 16B-aligned, breaks power-of-2 strides

template<int NV, bool RESID>
__global__ __launch_bounds__(256)
void fattn_kernel(const float* __restrict__ Qb, long long q_sb, long long q_sh, int q_sr,
                  const float* __restrict__ Kb, long long k_sb, long long k_sh, int k_sr,
                  const float* __restrict__ V0b, const float* __restrict__ V1b,
                  long long v_sb, long long v_sh, int v_sr,
                  float* __restrict__ O0b, float* __restrict__ O1b,
                  long long o_sb, long long o_sh, int o_sr)
{
    __shared__ float sQ[64 * FP];
    __shared__ float sKP[64 * FP];          // K tile, then re-used for P tile
    __shared__ float sV0[64 * FP];
    __shared__ float sV1[(NV == 2) ? 64 * FP : 4];

    const int t  = threadIdx.x;
    const int tx = t & 15, ty = t >> 4;
    const int bh = blockIdx.y;
    const int b = bh >> 3, h = bh & 7;
    const int i0 = blockIdx.x * 64;

    const float* Qg  = Qb  + (size_t)b * q_sb + (size_t)h * q_sh;
    const float* Kg  = Kb  + (size_t)b * k_sb + (size_t)h * k_sh;
    const float* V0g = V0b + (size_t)b * v_sb + (size_t)h * v_sh;
    const float* V1g = (NV == 2) ? (V1b + (size_t)b * v_sb + (size_t)h * v_sh) : nullptr;
    float* O0g = O0b + (size_t)b * o_sb + (size_t)h * o_sh;
    float* O1g = (NV == 2) ? (O1b + (size_t)b * o_sb + (size_t)h * o_sh) : nullptr;

    // Load Q tile (64x64): thread p-loop covers rows ty+16p, 16B per lane
#pragma unroll
    for (int p = 0; p < 4; p++) {
        int row = ty + 16 * p;
        *(float4*)&sQ[row * FP + tx * 4] =
            *(const float4*)(Qg + (size_t)(i0 + row) * q_sr + tx * 4);
    }

    float m[4], l[4];
    float O0[4][4], O1[(NV == 2) ? 4 : 1][4];
#pragma unroll
    for (int a = 0; a < 4; a++) {
        m[a] = -1e30f; l[a] = 0.f;
#pragma unroll
        for (int c = 0; c < 4; c++) O0[a][c] = 0.f;
        if constexpr (NV == 2)
#pragma unroll
            for (int c = 0; c < 4; c++) O1[a][c] = 0.f;
    }

    const float scale = 0.125f;

    for (int j0 = 0; j0 < N_; j0 += 64) {
        __syncthreads();   // prev tile's P/V reads done before overwrite
#pragma unroll
        for (int p = 0; p < 4; p++) {
            int row = ty + 16 * p;
            *(float4*)&sKP[row * FP + tx * 4] =
                *(const float4*)(Kg + (size_t)(j0 + row) * k_sr + tx * 4);
            *(float4*)&sV0[row * FP + tx * 4] =
                *(const float4*)(V0g + (size_t)(j0 + row) * v_sr + tx * 4);
            if constexpr (NV == 2)
                *(float4*)&sV1[row * FP + tx * 4] =
                    *(const float4*)(V1g + (size_t)(j0 + row) * v_sr + tx * 4);
        }
        __syncthreads();

        // ---- QK^T: S[a][b] = sum_d Q[ty+16a][d] * K[tx+16b][d]
        float s[4][4];
#pragma unroll
        for (int a = 0; a < 4; a++)
#pragma unroll
            for (int c = 0; c < 4; c++) s[a][c] = 0.f;
        for (int d0 = 0; d0 < 64; d0 += 4) {
            float4 qv[4], kv[4];
#pragma unroll
            for (int a = 0; a < 4; a++) qv[a] = *(const float4*)&sQ[(ty + 16 * a) * FP + d0];
#pragma unroll
            for (int c = 0; c < 4; c++) kv[c] = *(const float4*)&sKP[(tx + 16 * c) * FP + d0];
#pragma unroll
            for (int a = 0; a < 4; a++)
#pragma unroll
                for (int c = 0; c < 4; c++) {
                    s[a][c] += qv[a].x * kv[c].x + qv[a].y * kv[c].y
                             + qv[a].z * kv[c].z + qv[a].w * kv[c].w;
                }
        }

        // ---- online softmax update (no LDS; reduce across the 16 tx lanes)
        float alpha[4], mn[4];
#pragma unroll
        for (int a = 0; a < 4; a++) {
            float tm = fmaxf(fmaxf(s[a][0], s[a][1]), fmaxf(s[a][2], s[a][3])) * scale;
#pragma unroll
            for (int mk = 1; mk <= 8; mk <<= 1) tm = fmaxf(tm, __shfl_xor(tm, mk));
            mn[a] = fmaxf(m[a], tm);
            alpha[a] = __expf(m[a] - mn[a]);
            m[a] = mn[a];
            float rs = 0.f;
#pragma unroll
            for (int c = 0; c < 4; c++) {
                s[a][c] = __expf(s[a][c] * scale - mn[a]);
                rs += s[a][c];
            }
#pragma unroll
            for (int mk = 1; mk <= 8; mk <<= 1) rs += __shfl_xor(rs, mk);
            l[a] = l[a] * alpha[a] + rs;
#pragma unroll
            for (int c = 0; c < 4; c++) O0[a][c] *= alpha[a];
            if constexpr (NV == 2)
#pragma unroll
                for (int c = 0; c < 4; c++) O1[a][c] *= alpha[a];
        }

        __syncthreads();   // everyone done reading K from sKP
#pragma unroll
        for (int a = 0; a < 4; a++)
#pragma unroll
            for (int c = 0; c < 4; c++)
                sKP[(ty + 16 * a) * FP + tx + 16 * c] = s[a][c];
        __syncthreads();   // P visible

        // ---- PV: O[a][d] += P[ty+16a][j] * V[j][d],  d = tx*4..+3
        for (int jj = 0; jj < 64; jj += 4) {
            float4 pv[4];
#pragma unroll
            for (int a = 0; a < 4; a++) pv[a] = *(const float4*)&sKP[(ty + 16 * a) * FP + jj];
#pragma unroll
            for (int q = 0; q < 4; q++) {
                float4 vv0 = *(const float4*)&sV0[(jj + q) * FP + tx * 4];
                float pq;
#pragma unroll
                for (int a = 0; a < 4; a++) {
                    pq = (q == 0) ? pv[a].x : (q == 1) ? pv[a].y : (q == 2) ? pv[a].z : pv[a].w;
                    O0[a][0] += pq * vv0.x; O0[a][1] += pq * vv0.y;
                    O0[a][2] += pq * vv0.z; O0[a][3] += pq * vv0.w;
                }
                if constexpr (NV == 2) {
                    float4 vv1 = *(const float4*)&sV1[(jj + q) * FP + tx * 4];
#pragma unroll
                    for (int a = 0; a < 4; a++) {
                        pq = (q == 0) ? pv[a].x : (q == 1) ? pv[a].y : (q == 2) ? pv[a].z : pv[a].w;
                        O1[a][0] += pq * vv1.x; O1[a][1] += pq * vv1.y;
                        O1[a][2] += pq * vv1.z; O1[a][3] += pq * vv1.w;
                    }
                }
            }
        }
    }

    // ---- epilogue
#pragma unroll
    for (int a = 0; a < 4; a++) {
        float inv = 1.0f / l[a];
        int row = i0 + ty + 16 * a;
        float4 o0;
        o0.x = O0[a][0] * inv; o0.y = O0[a][1] * inv;
        o0.z = O0[a][2] * inv; o0.w = O0[a][3] * inv;
        if constexpr (RESID) {
            float4 r0 = *(const float4*)(V0g + (size_t)row * v_sr + tx * 4);
            o0.x += r0.x; o0.y += r0.y; o0.z += r0.z; o0.w += r0.w;
        }
        *(float4*)(O0g + (size_t)row * o_sr + tx * 4) = o0;
        if constexpr (NV == 2) {
            float4 o1;
            o1.x = O1[a][0] * inv; o1.y = O1[a][1] * inv;
            o1.z = O1[a][2] * inv; o1.w = O1[a][3] * inv;
            if constexpr (RESID) {
                float4 r1 = *(const float4*)(V1g + (size_t)row * v_sr + tx * 4);
                o1.x += r1.x; o1.y += r1.y; o1.z += r1.z; o1.w += r1.w;
            }
            *(float4*)(O1g + (size_t)row * o_sr + tx * 4) = o1;
        }
    }
}

// ---------------------------------------------------------------------------
extern "C" void kernel_launch(void* const* d_in, const int* in_sizes, int n_in,
                              void* d_out, int out_size, void* d_ws, size_t ws_size,
                              hipStream_t stream)
{
    const float* x1    = (const float*)d_in[0];
    const float* x2    = (const float*)d_in[1];
    const float* Wqkv1 = (const float*)d_in[2];
    const float* Wqkv2 = (const float*)d_in[3];
    const float* Wout1 = (const float*)d_in[4];
    const float* bout1 = (const float*)d_in[5];
    const float* Wout2 = (const float*)d_in[6];
    const float* bout2 = (const float*)d_in[7];
    const float* convw = (const float*)d_in[8];
    const float* convb = (const float*)d_in[9];

    const size_t QKV_ELEMS = (size_t)M_ * QKVC;       // 16,777,216
    const size_t BND_ELEMS = (size_t)M_ * INNER_;     //  4,194,304
    if (ws_size < (2 * QKV_ELEMS + 5 * BND_ELEMS) * sizeof(float)) return;

    float* ws   = (float*)d_ws;
    float* qkv1 = ws;
    float* qkv2 = qkv1 + QKV_ELEMS;
    float* MSg  = qkv2 + QKV_ELEMS;
    float* u1   = MSg + BND_ELEMS;
    float* u2   = u1 + BND_ELEMS;
    float* t1m  = u2 + BND_ELEMS;
    float* t2m  = t1m + BND_ELEMS;

    dim3 blk(256);

    // 1) QKV projections
    gemm_kernel<false><<<dim3(QKVC / 128, M_ / 128), blk, 0, stream>>>(
        x1, Wqkv1, nullptr, qkv1, M_, QKVC, DIM_);
    gemm_kernel<false><<<dim3(QKVC / 128, M_ / 128), blk, 0, stream>>>(
        x2, Wqkv2, nullptr, qkv2, M_, QKVC, DIM_);

    // 2) conv + sigmoid gate -> MSg
    convgate_kernel<<<dim3(M_), dim3(128), 0, stream>>>(qkv1, qkv2, convw, convb, MSg);

    // Stride descriptors
    const long long msg_sb = (long long)N_ * INNER_, msg_sh = HD_;
    const int       msg_sr = INNER_;
    const long long qkv_sb = (long long)N_ * QKVC, qkv_sh = HD_;
    const int       qkv_sr = QKVC;
    const long long u_sb = (long long)H_ * N_ * HD_, u_sh = (long long)N_ * HD_;
    const int       u_sr = HD_;

    // 3) Attention A: scores from MSg heads, apply to v1 & v2 with +v residual
    fattn_kernel<2, true><<<dim3(N_ / 64, B_ * H_), blk, 0, stream>>>(
        MSg, msg_sb, msg_sh, msg_sr,
        MSg, msg_sb, msg_sh, msg_sr,
        qkv1 + 2 * INNER_, qkv2 + 2 * INNER_, qkv_sb, qkv_sh, qkv_sr,
        u1, u2, u_sb, u_sh, u_sr);

    // 4) Attention B (stream 1 and 2): t = softmax(q k^T) @ u, merged-head out
    fattn_kernel<1, false><<<dim3(N_ / 64, B_ * H_), blk, 0, stream>>>(
        qkv1, qkv_sb, qkv_sh, qkv_sr,
        qkv1 + INNER_, qkv_sb, qkv_sh, qkv_sr,
        u1, nullptr, u_sb, u_sh, u_sr,
        t1m, nullptr, msg_sb, msg_sh, msg_sr);
    fattn_kernel<1, false><<<dim3(N_ / 64, B_ * H_), blk, 0, stream>>>(
        qkv2, qkv_sb, qkv_sh, qkv_sr,
        qkv2 + INNER_, qkv_sb, qkv_sh, qkv_sr,
        u2, nullptr, u_sb, u_sh, u_sr,
        t2m, nullptr, msg_sb, msg_sh, msg_sr);

    // 5) Output projections (bias, f32 out)
    float* out1 = (float*)d_out;
    float* out2 = out1 + (size_t)M_ * DIM_;
    gemm_kernel<true><<<dim3(DIM_ / 128, M_ / 128), blk, 0, stream>>>(
        t1m, Wout1, bout1, out1, M_, DIM_, DIM_);
    gemm_kernel<true><<<dim3(DIM_ / 128, M_ / 128), blk, 0, stream>>>(
        t2m, Wout2, bout2, out2, M_, DIM_, DIM_);
}

// Round 4
// 1194.239 us; speedup vs baseline: 2.6901x; 1.3892x over previous
//
#include <hip/hip_runtime.h>
#include <hip/hip_bf16.h>

// Problem constants
#define B_     8
#define N_     1024
#define DIM_   512
#define H_     8
#define HD_    64
#define INNER_ 512
#define QKVC   2048   // 4*INNER
#define M_     8192   // B*N

typedef __attribute__((ext_vector_type(8))) short short8;
typedef __attribute__((ext_vector_type(4))) float f32x4;
#define MFMA_BF16 __builtin_amdgcn_mfma_f32_16x16x32_bf16

__device__ __forceinline__ unsigned short f2b(float x) {
    __hip_bfloat16 h = __float2bfloat16(x);
    unsigned short u; __builtin_memcpy(&u, &h, 2); return u;
}
// pack bf16 hi/lo split of x into one u32: (hi<<16)|lo
__device__ __forceinline__ unsigned int packsplit(float x) {
    unsigned int hb = f2b(x);
    float fh = __uint_as_float(hb << 16);
    unsigned int lb = f2b(x - fh);
    return (hb << 16) | lb;
}
__device__ __forceinline__ void unpack8(const uint4& a0, const uint4& a1,
                                        short8& h, short8& l) {
    h[0]=(short)(a0.x>>16); l[0]=(short)a0.x;
    h[1]=(short)(a0.y>>16); l[1]=(short)a0.y;
    h[2]=(short)(a0.z>>16); l[2]=(short)a0.z;
    h[3]=(short)(a0.w>>16); l[3]=(short)a0.w;
    h[4]=(short)(a1.x>>16); l[4]=(short)a1.x;
    h[5]=(short)(a1.y>>16); l[5]=(short)a1.y;
    h[6]=(short)(a1.z>>16); l[6]=(short)a1.z;
    h[7]=(short)(a1.w>>16); l[7]=(short)a1.w;
}
__device__ __forceinline__ void split8(const float* v, short8& h, short8& l) {
#pragma unroll
    for (int i = 0; i < 8; i++) {
        unsigned int hb = f2b(v[i]);
        float fh = __uint_as_float(hb << 16);
        h[i] = (short)hb; l[i] = (short)f2b(v[i] - fh);
    }
}

// ---------------------------------------------------------------------------
// Tiled GEMM: C[M,N] = A[M,K] @ B[K,N] (+ bias). All f32. (unchanged, SIMT)
// ---------------------------------------------------------------------------
template<bool BIAS>
__global__ __launch_bounds__(256)
void gemm_kernel(const float* __restrict__ Ap, const float* __restrict__ Bw,
                 const float* __restrict__ bias, float* __restrict__ Cp,
                 int M, int N, int K)
{
    __shared__ float sA[16][128];
    __shared__ float sB[16][128];
    const int t  = threadIdx.x;
    const int tx = t & 15, ty = t >> 4;
    const int m0 = blockIdx.y * 128, n0 = blockIdx.x * 128;

    float acc[8][8];
#pragma unroll
    for (int i = 0; i < 8; i++)
#pragma unroll
        for (int j = 0; j < 8; j++) acc[i][j] = 0.f;

    const int ar = t >> 1;
    const int ak = (t & 1) * 8;
    const int bk = t >> 4;
    const int bc = (t & 15) * 8;

    for (int k0 = 0; k0 < K; k0 += 16) {
        {
            const float* ap = Ap + (size_t)(m0 + ar) * K + k0 + ak;
            float4 a0 = *(const float4*)ap;
            float4 a1 = *((const float4*)ap + 1);
            sA[ak + 0][ar] = a0.x; sA[ak + 1][ar] = a0.y;
            sA[ak + 2][ar] = a0.z; sA[ak + 3][ar] = a0.w;
            sA[ak + 4][ar] = a1.x; sA[ak + 5][ar] = a1.y;
            sA[ak + 6][ar] = a1.z; sA[ak + 7][ar] = a1.w;
        }
        {
            const float* bp = Bw + (size_t)(k0 + bk) * N + n0 + bc;
            float4 b0 = *(const float4*)bp;
            float4 b1 = *((const float4*)bp + 1);
            sB[bk][bc + 0] = b0.x; sB[bk][bc + 1] = b0.y;
            sB[bk][bc + 2] = b0.z; sB[bk][bc + 3] = b0.w;
            sB[bk][bc + 4] = b1.x; sB[bk][bc + 5] = b1.y;
            sB[bk][bc + 6] = b1.z; sB[bk][bc + 7] = b1.w;
        }
        __syncthreads();
#pragma unroll
        for (int kk = 0; kk < 16; kk++) {
            float a[8], b[8];
            float4 t0 = *(const float4*)&sA[kk][ty * 4];
            float4 t1 = *(const float4*)&sA[kk][64 + ty * 4];
            a[0] = t0.x; a[1] = t0.y; a[2] = t0.z; a[3] = t0.w;
            a[4] = t1.x; a[5] = t1.y; a[6] = t1.z; a[7] = t1.w;
            float4 s0 = *(const float4*)&sB[kk][tx * 4];
            float4 s1 = *(const float4*)&sB[kk][64 + tx * 4];
            b[0] = s0.x; b[1] = s0.y; b[2] = s0.z; b[3] = s0.w;
            b[4] = s1.x; b[5] = s1.y; b[6] = s1.z; b[7] = s1.w;
#pragma unroll
            for (int i = 0; i < 8; i++)
#pragma unroll
                for (int j = 0; j < 8; j++) acc[i][j] += a[i] * b[j];
        }
        __syncthreads();
    }

    float bv[8];
#pragma unroll
    for (int j = 0; j < 8; j++) {
        int col = n0 + ((j < 4) ? tx * 4 + j : 64 + tx * 4 + (j - 4));
        bv[j] = BIAS ? bias[col] : 0.f;
    }
#pragma unroll
    for (int i = 0; i < 8; i++) {
        int row = m0 + ((i < 4) ? ty * 4 + i : 64 + ty * 4 + (i - 4));
#pragma unroll
        for (int j = 0; j < 8; j++) {
            int col = n0 + ((j < 4) ? tx * 4 + j : 64 + tx * 4 + (j - 4));
            Cp[(size_t)row * N + col] = acc[i][j] + bv[j];
        }
    }
}

// ---------------------------------------------------------------------------
// Depthwise conv (k=5, pad=2) over feature axis + sigmoid gate. (unchanged)
// ---------------------------------------------------------------------------
__global__ __launch_bounds__(128)
void convgate_kernel(const float* __restrict__ qkv1, const float* __restrict__ qkv2,
                     const float* __restrict__ convw,
                     const float* __restrict__ convb,
                     float* __restrict__ MSg)
{
    __shared__ float ms[INNER_];
    const int blk = blockIdx.x;
    const int n = blk & (N_ - 1);
    const int t = threadIdx.x;

    const float4* q1 = (const float4*)(qkv1 + (size_t)blk * QKVC + 3 * INNER_);
    const float4* q2 = (const float4*)(qkv2 + (size_t)blk * QKVC + 3 * INNER_);
    float4 v1 = q1[t], v2 = q2[t];
    float4 s;
    s.x = v1.x + v2.x; s.y = v1.y + v2.y; s.z = v1.z + v2.z; s.w = v1.w + v2.w;
    *(float4*)&ms[t * 4] = s;
    __syncthreads();

    float w[5];
#pragma unroll
    for (int k = 0; k < 5; k++) w[k] = convw[n * 5 + k];
    const float cb = convb[n];

    float out[4];
#pragma unroll
    for (int ff = 0; ff < 4; ff++) {
        int f = t * 4 + ff;
        float A = cb;
#pragma unroll
        for (int k = 0; k < 5; k++) {
            int idx = f + k - 2;
            if (idx >= 0 && idx < INNER_) A += ms[idx] * w[k];
        }
        float sg = 1.f / (1.f + __expf(-A));
        out[ff] = ms[f] * sg;
    }
    *(float4*)&MSg[(size_t)blk * INNER_ + t * 4] = make_float4(out[0], out[1], out[2], out[3]);
}

// ---------------------------------------------------------------------------
// MFMA flash attention (bf16 hi/lo split, f32 accumulate).
// Block = (b,h) x 64 q-rows, 4 waves x 16 q-rows. j-tiles of 64 keys.
// S^T = K.Q^T per wave (A=K frag, B=Q frag; both "row=lane&15,k=quad*8+j").
// Online softmax per lane (col q = lane&15), shfl_xor(16,32) reductions.
// K/V staged in LDS as u32 (bf16hi<<16|bf16lo), V transposed, XOR-swizzled
// chunks (pitch 64 u32, chunk^ (row&15)) -> conflict-floor b128 traffic.
// P: f32 LDS rows (pitch 65), re-split to bf16 frags for PV.
// ---------------------------------------------------------------------------
template<int NV, bool RESID>
__global__ __launch_bounds__(256)
void mattn_kernel(const float* __restrict__ Qb, long long q_sb, long long q_sh, int q_sr,
                  const float* __restrict__ Kb, long long k_sb, long long k_sh, int k_sr,
                  const float* __restrict__ V0b, const float* __restrict__ V1b,
                  long long v_sb, long long v_sh, int v_sr,
                  float* __restrict__ O0b, float* __restrict__ O1b,
                  long long o_sb, long long o_sh, int o_sr)
{
    __shared__ __align__(16) unsigned int sKp[64 * 64];
    __shared__ __align__(16) unsigned int sV0[64 * 64];
    __shared__ __align__(16) unsigned int sV1[(NV == 2) ? 64 * 64 : 4];
    __shared__ __align__(16) float sP[64 * 65];

    const int t    = threadIdx.x;
    const int w    = t >> 6;        // wave 0..3
    const int lane = t & 63;
    const int n    = lane & 15;
    const int quad = lane >> 4;

    const int bh = blockIdx.y;
    const int b  = bh >> 3, h = bh & 7;
    const int i0 = blockIdx.x * 64;

    const float* Qg  = Qb  + (size_t)b * q_sb + (size_t)h * q_sh;
    const float* Kg  = Kb  + (size_t)b * k_sb + (size_t)h * k_sh;
    const float* V0g = V0b + (size_t)b * v_sb + (size_t)h * v_sh;
    const float* V1g = (NV == 2) ? (V1b + (size_t)b * v_sb + (size_t)h * v_sh) : nullptr;
    float* O0g = O0b + (size_t)b * o_sb + (size_t)h * o_sh;
    float* O1g = (NV == 2) ? (O1b + (size_t)b * o_sb + (size_t)h * o_sh) : nullptr;

    // ---- Q fragments (persistent): rows i0+16w+n, d = 32s + 8*quad + 0..7
    short8 Qh[2], Ql[2];
#pragma unroll
    for (int s = 0; s < 2; s++) {
        const float* qp = Qg + (size_t)(i0 + 16 * w + n) * q_sr + 32 * s + 8 * quad;
        float qv[8];
        float4 q0 = *(const float4*)qp;
        float4 q1 = *(const float4*)(qp + 4);
        qv[0]=q0.x; qv[1]=q0.y; qv[2]=q0.z; qv[3]=q0.w;
        qv[4]=q1.x; qv[5]=q1.y; qv[6]=q1.z; qv[7]=q1.w;
        split8(qv, Qh[s], Ql[s]);
    }

    float m_ = -1e30f, l_ = 0.f;
    f32x4 O0a[4], O1a[(NV == 2) ? 4 : 1];
#pragma unroll
    for (int nt = 0; nt < 4; nt++) { O0a[nt] = (f32x4){0.f,0.f,0.f,0.f}; }
    if constexpr (NV == 2) {
#pragma unroll
        for (int nt = 0; nt < 4; nt++) O1a[nt] = (f32x4){0.f,0.f,0.f,0.f};
    }

    const float scale = 0.125f;
    const int prow = (16 * w + n) * 65;

    for (int j0 = 0; j0 < N_; j0 += 64) {
        __syncthreads();   // staging buffers free (prev tile's reads done)

        // ---- stage K: row-major, u32-packed, chunk swizzle c^(key&15)
#pragma unroll
        for (int i = 0; i < 4; i++) {
            int key = (t >> 4) + 16 * i;
            int dg  = t & 15;
            const float* kp = Kg + (size_t)(j0 + key) * k_sr + dg * 4;
            float4 kv = *(const float4*)kp;
            uint4 pk;
            pk.x = packsplit(kv.x); pk.y = packsplit(kv.y);
            pk.z = packsplit(kv.z); pk.w = packsplit(kv.w);
            *(uint4*)&sKp[key * 64 + ((dg ^ (key & 15)) << 2)] = pk;
        }
        // ---- stage V (transposed: rows = d, cols = j), same packing/swizzle
#pragma unroll
        for (int i = 0; i < 4; i++) {
            int j  = ((t >> 2) & 15) + 16 * i;
            int d0 = (t & 3) * 4 + (t >> 6) * 16;
            const float* vp = V0g + (size_t)(j0 + j) * v_sr + d0;
            float4 vv = *(const float4*)vp;
            int jc = j >> 2, jm = j & 3;
            sV0[(d0+0)*64 + ((jc ^ ((d0+0)&15))<<2) + jm] = packsplit(vv.x);
            sV0[(d0+1)*64 + ((jc ^ ((d0+1)&15))<<2) + jm] = packsplit(vv.y);
            sV0[(d0+2)*64 + ((jc ^ ((d0+2)&15))<<2) + jm] = packsplit(vv.z);
            sV0[(d0+3)*64 + ((jc ^ ((d0+3)&15))<<2) + jm] = packsplit(vv.w);
            if constexpr (NV == 2) {
                const float* vp1 = V1g + (size_t)(j0 + j) * v_sr + d0;
                float4 v1v = *(const float4*)vp1;
                sV1[(d0+0)*64 + ((jc ^ ((d0+0)&15))<<2) + jm] = packsplit(v1v.x);
                sV1[(d0+1)*64 + ((jc ^ ((d0+1)&15))<<2) + jm] = packsplit(v1v.y);
                sV1[(d0+2)*64 + ((jc ^ ((d0+2)&15))<<2) + jm] = packsplit(v1v.z);
                sV1[(d0+3)*64 + ((jc ^ ((d0+3)&15))<<2) + jm] = packsplit(v1v.w);
            }
        }
        __syncthreads();

        // ---- S^T = K.Q^T : accS[mt] covers keys 16mt..16mt+15 x q 0..15
        f32x4 accS[4];
#pragma unroll
        for (int mt = 0; mt < 4; mt++) accS[mt] = (f32x4){0.f,0.f,0.f,0.f};
#pragma unroll
        for (int s = 0; s < 2; s++) {
#pragma unroll
            for (int mt = 0; mt < 4; mt++) {
                int key = 16 * mt + n;
                int base = key * 64;
                int c0 = 8 * s + 2 * quad;
                uint4 a0 = *(const uint4*)&sKp[base + ((c0 ^ n) << 2)];
                uint4 a1 = *(const uint4*)&sKp[base + (((c0 + 1) ^ n) << 2)];
                short8 kh, kl;
                unpack8(a0, a1, kh, kl);
                accS[mt] = MFMA_BF16(kl, Qh[s], accS[mt], 0, 0, 0);
                accS[mt] = MFMA_BF16(kh, Ql[s], accS[mt], 0, 0, 0);
                accS[mt] = MFMA_BF16(kh, Qh[s], accS[mt], 0, 0, 0);
            }
        }

        // ---- online softmax (per lane: col q = lane&15; keys 16mt+4quad+r)
        float tmax = -1e30f;
#pragma unroll
        for (int mt = 0; mt < 4; mt++)
#pragma unroll
            for (int r = 0; r < 4; r++) tmax = fmaxf(tmax, accS[mt][r]);
        tmax *= scale;
        tmax = fmaxf(tmax, __shfl_xor(tmax, 16));
        tmax = fmaxf(tmax, __shfl_xor(tmax, 32));
        float mnew = fmaxf(m_, tmax);
        float alpha = __expf(m_ - mnew);
        m_ = mnew;
        float rsum = 0.f;
#pragma unroll
        for (int mt = 0; mt < 4; mt++)
#pragma unroll
            for (int r = 0; r < 4; r++) {
                float p = __expf(accS[mt][r] * scale - mnew);
                sP[prow + 16 * mt + 4 * quad + r] = p;
                rsum += p;
            }
        rsum += __shfl_xor(rsum, 16);
        rsum += __shfl_xor(rsum, 32);
        l_ = l_ * alpha + rsum;

        // rescale O accumulators: row r of C-frag = q-row quad*4+r
        float ar[4];
#pragma unroll
        for (int r = 0; r < 4; r++) ar[r] = __shfl(alpha, (quad << 2) + r);
#pragma unroll
        for (int nt = 0; nt < 4; nt++) {
#pragma unroll
            for (int r = 0; r < 4; r++) O0a[nt][r] *= ar[r];
            if constexpr (NV == 2)
#pragma unroll
                for (int r = 0; r < 4; r++) O1a[nt][r] *= ar[r];
        }

        // ---- P frags (A-operand): lane q = lane&15, j = 32s + 8quad + 0..7
        short8 Ph[2], Pl[2];
#pragma unroll
        for (int s = 0; s < 2; s++) {
            float pv[8];
#pragma unroll
            for (int jj = 0; jj < 8; jj++)
                pv[jj] = sP[prow + 32 * s + 8 * quad + jj];
            split8(pv, Ph[s], Pl[s]);
        }

        // ---- PV: O[q][d] += P.V ; B-frag from transposed sVt
#pragma unroll
        for (int s = 0; s < 2; s++) {
#pragma unroll
            for (int nt = 0; nt < 4; nt++) {
                int d = 16 * nt + n;
                int base = d * 64;
                int c0 = 8 * s + 2 * quad;
                int sw = d & 15;
                uint4 b0 = *(const uint4*)&sV0[base + ((c0 ^ sw) << 2)];
                uint4 b1 = *(const uint4*)&sV0[base + (((c0 + 1) ^ sw) << 2)];
                short8 vh, vl;
                unpack8(b0, b1, vh, vl);
                O0a[nt] = MFMA_BF16(Pl[s], vh, O0a[nt], 0, 0, 0);
                O0a[nt] = MFMA_BF16(Ph[s], vl, O0a[nt], 0, 0, 0);
                O0a[nt] = MFMA_BF16(Ph[s], vh, O0a[nt], 0, 0, 0);
                if constexpr (NV == 2) {
                    uint4 c0v = *(const uint4*)&sV1[base + ((c0 ^ sw) << 2)];
                    uint4 c1v = *(const uint4*)&sV1[base + (((c0 + 1) ^ sw) << 2)];
                    short8 wh, wl;
                    unpack8(c0v, c1v, wh, wl);
                    O1a[nt] = MFMA_BF16(Pl[s], wh, O1a[nt], 0, 0, 0);
                    O1a[nt] = MFMA_BF16(Ph[s], wl, O1a[nt], 0, 0, 0);
                    O1a[nt] = MFMA_BF16(Ph[s], wh, O1a[nt], 0, 0, 0);
                }
            }
        }
    }

    // ---- epilogue: normalize (l per q-row via shfl), +V residual, store
    float linv[4];
#pragma unroll
    for (int r = 0; r < 4; r++) linv[r] = 1.0f / __shfl(l_, (quad << 2) + r);
#pragma unroll
    for (int r = 0; r < 4; r++) {
        int row = i0 + 16 * w + 4 * quad + r;
#pragma unroll
        for (int nt = 0; nt < 4; nt++) {
            int col = 16 * nt + n;
            float v = O0a[nt][r] * linv[r];
            if constexpr (RESID) v += V0g[(size_t)row * v_sr + col];
            O0g[(size_t)row * o_sr + col] = v;
            if constexpr (NV == 2) {
                float v1 = O1a[nt][r] * linv[r];
                if constexpr (RESID) v1 += V1g[(size_t)row * v_sr + col];
                O1g[(size_t)row * o_sr + col] = v1;
            }
        }
    }
}

// ---------------------------------------------------------------------------
extern "C" void kernel_launch(void* const* d_in, const int* in_sizes, int n_in,
                              void* d_out, int out_size, void* d_ws, size_t ws_size,
                              hipStream_t stream)
{
    const float* x1    = (const float*)d_in[0];
    const float* x2    = (const float*)d_in[1];
    const float* Wqkv1 = (const float*)d_in[2];
    const float* Wqkv2 = (const float*)d_in[3];
    const float* Wout1 = (const float*)d_in[4];
    const float* bout1 = (const float*)d_in[5];
    const float* Wout2 = (const float*)d_in[6];
    const float* bout2 = (const float*)d_in[7];
    const float* convw = (const float*)d_in[8];
    const float* convb = (const float*)d_in[9];

    const size_t QKV_ELEMS = (size_t)M_ * QKVC;
    const size_t BND_ELEMS = (size_t)M_ * INNER_;
    if (ws_size < (2 * QKV_ELEMS + 5 * BND_ELEMS) * sizeof(float)) return;

    float* ws   = (float*)d_ws;
    float* qkv1 = ws;
    float* qkv2 = qkv1 + QKV_ELEMS;
    float* MSg  = qkv2 + QKV_ELEMS;
    float* u1   = MSg + BND_ELEMS;
    float* u2   = u1 + BND_ELEMS;
    float* t1m  = u2 + BND_ELEMS;
    float* t2m  = t1m + BND_ELEMS;

    dim3 blk(256);

    // 1) QKV projections
    gemm_kernel<false><<<dim3(QKVC / 128, M_ / 128), blk, 0, stream>>>(
        x1, Wqkv1, nullptr, qkv1, M_, QKVC, DIM_);
    gemm_kernel<false><<<dim3(QKVC / 128, M_ / 128), blk, 0, stream>>>(
        x2, Wqkv2, nullptr, qkv2, M_, QKVC, DIM_);

    // 2) conv + sigmoid gate -> MSg
    convgate_kernel<<<dim3(M_), dim3(128), 0, stream>>>(qkv1, qkv2, convw, convb, MSg);

    // Stride descriptors
    const long long msg_sb = (long long)N_ * INNER_, msg_sh = HD_;
    const int       msg_sr = INNER_;
    const long long qkv_sb = (long long)N_ * QKVC, qkv_sh = HD_;
    const int       qkv_sr = QKVC;
    const long long u_sb = (long long)H_ * N_ * HD_, u_sh = (long long)N_ * HD_;
    const int       u_sr = HD_;

    // 3) Attention A: scores from MSg heads, apply to v1 & v2 with +v residual
    mattn_kernel<2, true><<<dim3(N_ / 64, B_ * H_), blk, 0, stream>>>(
        MSg, msg_sb, msg_sh, msg_sr,
        MSg, msg_sb, msg_sh, msg_sr,
        qkv1 + 2 * INNER_, qkv2 + 2 * INNER_, qkv_sb, qkv_sh, qkv_sr,
        u1, u2, u_sb, u_sh, u_sr);

    // 4) Attention B (stream 1 and 2)
    mattn_kernel<1, false><<<dim3(N_ / 64, B_ * H_), blk, 0, stream>>>(
        qkv1, qkv_sb, qkv_sh, qkv_sr,
        qkv1 + INNER_, qkv_sb, qkv_sh, qkv_sr,
        u1, nullptr, u_sb, u_sh, u_sr,
        t1m, nullptr, msg_sb, msg_sh, msg_sr);
    mattn_kernel<1, false><<<dim3(N_ / 64, B_ * H_), blk, 0, stream>>>(
        qkv2, qkv_sb, qkv_sh, qkv_sr,
        qkv2 + INNER_, qkv_sb, qkv_sh, qkv_sr,
        u2, nullptr, u_sb, u_sh, u_sr,
        t2m, nullptr, msg_sb, msg_sh, msg_sr);

    // 5) Output projections (bias, f32 out)
    float* out1 = (float*)d_out;
    float* out2 = out1 + (size_t)M_ * DIM_;
    gemm_kernel<true><<<dim3(DIM_ / 128, M_ / 128), blk, 0, stream>>>(
        t1m, Wout1, bout1, out1, M_, DIM_, DIM_);
    gemm_kernel<true><<<dim3(DIM_ / 128, M_ / 128), blk, 0, stream>>>(
        t2m, Wout2, bout2, out2, M_, DIM_, DIM_);
}

// Round 5
// 829.779 us; speedup vs baseline: 3.8717x; 1.4392x over previous
//
#include <hip/hip_runtime.h>
#include <hip/hip_bf16.h>

// Problem constants
#define B_     8
#define N_     1024
#define DIM_   512
#define H_     8
#define HD_    64
#define INNER_ 512
#define QKVC   2048   // 4*INNER
#define M_     8192   // B*N

typedef __attribute__((ext_vector_type(8))) short short8;
typedef __attribute__((ext_vector_type(4))) float f32x4;
#define MFMA_BF16 __builtin_amdgcn_mfma_f32_16x16x32_bf16

__device__ __forceinline__ unsigned short f2b(float x) {
    __hip_bfloat16 h = __float2bfloat16(x);
    unsigned short u; __builtin_memcpy(&u, &h, 2); return u;
}
// pack bf16 hi/lo split of x into one u32: (hi<<16)|lo
__device__ __forceinline__ unsigned int packsplit(float x) {
    unsigned int hb = f2b(x);
    float fh = __uint_as_float(hb << 16);
    unsigned int lb = f2b(x - fh);
    return (hb << 16) | lb;
}
__device__ __forceinline__ void unpack8(const uint4& a0, const uint4& a1,
                                        short8& h, short8& l) {
    h[0]=(short)(a0.x>>16); l[0]=(short)a0.x;
    h[1]=(short)(a0.y>>16); l[1]=(short)a0.y;
    h[2]=(short)(a0.z>>16); l[2]=(short)a0.z;
    h[3]=(short)(a0.w>>16); l[3]=(short)a0.w;
    h[4]=(short)(a1.x>>16); l[4]=(short)a1.x;
    h[5]=(short)(a1.y>>16); l[5]=(short)a1.y;
    h[6]=(short)(a1.z>>16); l[6]=(short)a1.z;
    h[7]=(short)(a1.w>>16); l[7]=(short)a1.w;
}
__device__ __forceinline__ void split8(const float* v, short8& h, short8& l) {
#pragma unroll
    for (int i = 0; i < 8; i++) {
        unsigned int hb = f2b(v[i]);
        float fh = __uint_as_float(hb << 16);
        h[i] = (short)hb; l[i] = (short)f2b(v[i] - fh);
    }
}

// ---------------------------------------------------------------------------
// Pack kernels: f32 -> u32 (bf16hi<<16 | bf16lo)
// ---------------------------------------------------------------------------
__global__ __launch_bounds__(256)
void pack_f32(const float* __restrict__ in, unsigned int* __restrict__ out)
{
    size_t i = ((size_t)blockIdx.x * 256 + threadIdx.x) * 4;
    float4 v = *(const float4*)(in + i);
    uint4 p;
    p.x = packsplit(v.x); p.y = packsplit(v.y);
    p.z = packsplit(v.z); p.w = packsplit(v.w);
    *(uint4*)(out + i) = p;
}

// W[k][n] (f32, K=512 rows, N cols) -> Wt[n][k] packed u32
__global__ __launch_bounds__(256)
void pack_wt(const float* __restrict__ W, unsigned int* __restrict__ Wt, int N)
{
    const int n = blockIdx.x * 256 + threadIdx.x;
    const int k0 = blockIdx.y * 4;
    uint4 p;
    p.x = packsplit(W[(size_t)(k0 + 0) * N + n]);
    p.y = packsplit(W[(size_t)(k0 + 1) * N + n]);
    p.z = packsplit(W[(size_t)(k0 + 2) * N + n]);
    p.w = packsplit(W[(size_t)(k0 + 3) * N + n]);
    *(uint4*)&Wt[(size_t)n * 512 + k0] = p;
}

// ---------------------------------------------------------------------------
// MFMA GEMM with bf16 hi/lo split (3 MFMA per product), K fixed = 512.
// A: packed u32 [M][512] row-major. Bt: packed u32 [N][512] (i.e. B^T).
// C: f32 [M][N] (+bias). 128x128 tile, BK=32, 4 waves (2x2, 64x64 each,
// 4x4 grid of 16x16x32). LDS: hi/lo ushort planes interleaved per row
// (row = 64B hi | 64B lo), XOR chunk swizzle (16B chunks, c ^ (row&7)) ->
// frag loads are direct ds_read_b128, no unpack VALU in the K-loop.
// ---------------------------------------------------------------------------
template<bool BIAS>
__global__ __launch_bounds__(256)
void gemm_mfma(const unsigned int* __restrict__ Ap, const unsigned int* __restrict__ Btp,
               const float* __restrict__ bias, float* __restrict__ Cp,
               int M, int N)
{
    const int K = 512;
    __shared__ __align__(16) unsigned short sA[128 * 64];
    __shared__ __align__(16) unsigned short sB[128 * 64];

    const int t    = threadIdx.x;
    const int lane = t & 63;
    const int w    = t >> 6;
    const int n16  = lane & 15, quad = lane >> 4;
    const int wm   = w >> 1, wn = w & 1;
    const int m0 = blockIdx.y * 128, n0 = blockIdx.x * 128;

    f32x4 acc[4][4];
#pragma unroll
    for (int mt = 0; mt < 4; mt++)
#pragma unroll
        for (int nt = 0; nt < 4; nt++) acc[mt][nt] = (f32x4){0.f, 0.f, 0.f, 0.f};

    const int srow = t >> 1;              // staging row 0..127
    const int kb   = (t & 1) * 16;        // staging k base within 32-chunk
    const unsigned int* ag = Ap  + (size_t)(m0 + srow) * K + kb;
    const unsigned int* bg = Btp + (size_t)(n0 + srow) * K + kb;
    const int s7s = srow & 7;
    unsigned short* swA = &sA[srow * 64];
    unsigned short* swB = &sB[srow * 64];

    for (int k0 = 0; k0 < K; k0 += 32) {
        __syncthreads();
#pragma unroll
        for (int i = 0; i < 4; i++) {
            const int kk = kb + i * 4;          // u32 k within chunk (0..28)
            const int ch = kk >> 3;             // logical hi chunk 0..3
            const int ho = kk & 4;              // ushort offset within chunk
            const int c_hi = ((ch    ) ^ s7s) << 3;
            const int c_lo = ((ch + 4) ^ s7s) << 3;
            uint4 va = *(const uint4*)(ag + k0 + i * 4);
            uint4 vb = *(const uint4*)(bg + k0 + i * 4);
            uint2 ha, la, hb, lb;
            ha.x = (va.y & 0xFFFF0000u) | (va.x >> 16);
            ha.y = (va.w & 0xFFFF0000u) | (va.z >> 16);
            la.x = (va.y << 16) | (va.x & 0xFFFFu);
            la.y = (va.w << 16) | (va.z & 0xFFFFu);
            hb.x = (vb.y & 0xFFFF0000u) | (vb.x >> 16);
            hb.y = (vb.w & 0xFFFF0000u) | (vb.z >> 16);
            lb.x = (vb.y << 16) | (vb.x & 0xFFFFu);
            lb.y = (vb.w << 16) | (vb.z & 0xFFFFu);
            *(uint2*)&swA[c_hi + ho] = ha;
            *(uint2*)&swA[c_lo + ho] = la;
            *(uint2*)&swB[c_hi + ho] = hb;
            *(uint2*)&swB[c_lo + ho] = lb;
        }
        __syncthreads();

        short8 Ah[4], Al[4];
#pragma unroll
        for (int mt = 0; mt < 4; mt++) {
            const int row = 64 * wm + 16 * mt + n16;
            const int base = row * 64;
            const int s7 = row & 7;
            Ah[mt] = *(const short8*)&sA[base + (((quad    ) ^ s7) << 3)];
            Al[mt] = *(const short8*)&sA[base + (((quad + 4) ^ s7) << 3)];
        }
#pragma unroll
        for (int nt = 0; nt < 4; nt++) {
            const int row = 64 * wn + 16 * nt + n16;
            const int base = row * 64;
            const int s7 = row & 7;
            short8 Bh = *(const short8*)&sB[base + (((quad    ) ^ s7) << 3)];
            short8 Bl = *(const short8*)&sB[base + (((quad + 4) ^ s7) << 3)];
#pragma unroll
            for (int mt = 0; mt < 4; mt++) {
                acc[mt][nt] = MFMA_BF16(Ah[mt], Bh, acc[mt][nt], 0, 0, 0);
                acc[mt][nt] = MFMA_BF16(Al[mt], Bh, acc[mt][nt], 0, 0, 0);
                acc[mt][nt] = MFMA_BF16(Ah[mt], Bl, acc[mt][nt], 0, 0, 0);
            }
        }
    }

    float bv[4];
#pragma unroll
    for (int nt = 0; nt < 4; nt++)
        bv[nt] = BIAS ? bias[n0 + 64 * wn + 16 * nt + n16] : 0.f;
#pragma unroll
    for (int mt = 0; mt < 4; mt++) {
        const int rbase = m0 + 64 * wm + 16 * mt + 4 * quad;
#pragma unroll
        for (int r = 0; r < 4; r++) {
#pragma unroll
            for (int nt = 0; nt < 4; nt++) {
                const int col = n0 + 64 * wn + 16 * nt + n16;
                Cp[(size_t)(rbase + r) * N + col] = acc[mt][nt][r] + bv[nt];
            }
        }
    }
}

// ---------------------------------------------------------------------------
// Depthwise conv (k=5, pad=2) over feature axis + sigmoid gate. (unchanged)
// ---------------------------------------------------------------------------
__global__ __launch_bounds__(128)
void convgate_kernel(const float* __restrict__ qkv1, const float* __restrict__ qkv2,
                     const float* __restrict__ convw,
                     const float* __restrict__ convb,
                     float* __restrict__ MSg)
{
    __shared__ float ms[INNER_];
    const int blk = blockIdx.x;
    const int n = blk & (N_ - 1);
    const int t = threadIdx.x;

    const float4* q1 = (const float4*)(qkv1 + (size_t)blk * QKVC + 3 * INNER_);
    const float4* q2 = (const float4*)(qkv2 + (size_t)blk * QKVC + 3 * INNER_);
    float4 v1 = q1[t], v2 = q2[t];
    float4 s;
    s.x = v1.x + v2.x; s.y = v1.y + v2.y; s.z = v1.z + v2.z; s.w = v1.w + v2.w;
    *(float4*)&ms[t * 4] = s;
    __syncthreads();

    float w[5];
#pragma unroll
    for (int k = 0; k < 5; k++) w[k] = convw[n * 5 + k];
    const float cb = convb[n];

    float out[4];
#pragma unroll
    for (int ff = 0; ff < 4; ff++) {
        int f = t * 4 + ff;
        float A = cb;
#pragma unroll
        for (int k = 0; k < 5; k++) {
            int idx = f + k - 2;
            if (idx >= 0 && idx < INNER_) A += ms[idx] * w[k];
        }
        float sg = 1.f / (1.f + __expf(-A));
        out[ff] = ms[f] * sg;
    }
    *(float4*)&MSg[(size_t)blk * INNER_ + t * 4] = make_float4(out[0], out[1], out[2], out[3]);
}

// ---------------------------------------------------------------------------
// MFMA flash attention (unchanged from round 4 except PACKO epilogue).
// ---------------------------------------------------------------------------
template<int NV, bool RESID, bool PACKO>
__global__ __launch_bounds__(256)
void mattn_kernel(const float* __restrict__ Qb, long long q_sb, long long q_sh, int q_sr,
                  const float* __restrict__ Kb, long long k_sb, long long k_sh, int k_sr,
                  const float* __restrict__ V0b, const float* __restrict__ V1b,
                  long long v_sb, long long v_sh, int v_sr,
                  float* __restrict__ O0b, float* __restrict__ O1b,
                  long long o_sb, long long o_sh, int o_sr)
{
    __shared__ __align__(16) unsigned int sKp[64 * 64];
    __shared__ __align__(16) unsigned int sV0[64 * 64];
    __shared__ __align__(16) unsigned int sV1[(NV == 2) ? 64 * 64 : 4];
    __shared__ __align__(16) float sP[64 * 65];

    const int t    = threadIdx.x;
    const int w    = t >> 6;
    const int lane = t & 63;
    const int n    = lane & 15;
    const int quad = lane >> 4;

    const int bh = blockIdx.y;
    const int b  = bh >> 3, h = bh & 7;
    const int i0 = blockIdx.x * 64;

    const float* Qg  = Qb  + (size_t)b * q_sb + (size_t)h * q_sh;
    const float* Kg  = Kb  + (size_t)b * k_sb + (size_t)h * k_sh;
    const float* V0g = V0b + (size_t)b * v_sb + (size_t)h * v_sh;
    const float* V1g = (NV == 2) ? (V1b + (size_t)b * v_sb + (size_t)h * v_sh) : nullptr;
    float* O0g = O0b + (size_t)b * o_sb + (size_t)h * o_sh;
    float* O1g = (NV == 2) ? (O1b + (size_t)b * o_sb + (size_t)h * o_sh) : nullptr;

    short8 Qh[2], Ql[2];
#pragma unroll
    for (int s = 0; s < 2; s++) {
        const float* qp = Qg + (size_t)(i0 + 16 * w + n) * q_sr + 32 * s + 8 * quad;
        float qv[8];
        float4 q0 = *(const float4*)qp;
        float4 q1 = *(const float4*)(qp + 4);
        qv[0]=q0.x; qv[1]=q0.y; qv[2]=q0.z; qv[3]=q0.w;
        qv[4]=q1.x; qv[5]=q1.y; qv[6]=q1.z; qv[7]=q1.w;
        split8(qv, Qh[s], Ql[s]);
    }

    float m_ = -1e30f, l_ = 0.f;
    f32x4 O0a[4], O1a[(NV == 2) ? 4 : 1];
#pragma unroll
    for (int nt = 0; nt < 4; nt++) { O0a[nt] = (f32x4){0.f,0.f,0.f,0.f}; }
    if constexpr (NV == 2) {
#pragma unroll
        for (int nt = 0; nt < 4; nt++) O1a[nt] = (f32x4){0.f,0.f,0.f,0.f};
    }

    const float scale = 0.125f;
    const int prow = (16 * w + n) * 65;

    for (int j0 = 0; j0 < N_; j0 += 64) {
        __syncthreads();

#pragma unroll
        for (int i = 0; i < 4; i++) {
            int key = (t >> 4) + 16 * i;
            int dg  = t & 15;
            const float* kp = Kg + (size_t)(j0 + key) * k_sr + dg * 4;
            float4 kv = *(const float4*)kp;
            uint4 pk;
            pk.x = packsplit(kv.x); pk.y = packsplit(kv.y);
            pk.z = packsplit(kv.z); pk.w = packsplit(kv.w);
            *(uint4*)&sKp[key * 64 + ((dg ^ (key & 15)) << 2)] = pk;
        }
#pragma unroll
        for (int i = 0; i < 4; i++) {
            int j  = ((t >> 2) & 15) + 16 * i;
            int d0 = (t & 3) * 4 + (t >> 6) * 16;
            const float* vp = V0g + (size_t)(j0 + j) * v_sr + d0;
            float4 vv = *(const float4*)vp;
            int jc = j >> 2, jm = j & 3;
            sV0[(d0+0)*64 + ((jc ^ ((d0+0)&15))<<2) + jm] = packsplit(vv.x);
            sV0[(d0+1)*64 + ((jc ^ ((d0+1)&15))<<2) + jm] = packsplit(vv.y);
            sV0[(d0+2)*64 + ((jc ^ ((d0+2)&15))<<2) + jm] = packsplit(vv.z);
            sV0[(d0+3)*64 + ((jc ^ ((d0+3)&15))<<2) + jm] = packsplit(vv.w);
            if constexpr (NV == 2) {
                const float* vp1 = V1g + (size_t)(j0 + j) * v_sr + d0;
                float4 v1v = *(const float4*)vp1;
                sV1[(d0+0)*64 + ((jc ^ ((d0+0)&15))<<2) + jm] = packsplit(v1v.x);
                sV1[(d0+1)*64 + ((jc ^ ((d0+1)&15))<<2) + jm] = packsplit(v1v.y);
                sV1[(d0+2)*64 + ((jc ^ ((d0+2)&15))<<2) + jm] = packsplit(v1v.z);
                sV1[(d0+3)*64 + ((jc ^ ((d0+3)&15))<<2) + jm] = packsplit(v1v.w);
            }
        }
        __syncthreads();

        f32x4 accS[4];
#pragma unroll
        for (int mt = 0; mt < 4; mt++) accS[mt] = (f32x4){0.f,0.f,0.f,0.f};
#pragma unroll
        for (int s = 0; s < 2; s++) {
#pragma unroll
            for (int mt = 0; mt < 4; mt++) {
                int key = 16 * mt + n;
                int base = key * 64;
                int c0 = 8 * s + 2 * quad;
                uint4 a0 = *(const uint4*)&sKp[base + ((c0 ^ n) << 2)];
                uint4 a1 = *(const uint4*)&sKp[base + (((c0 + 1) ^ n) << 2)];
                short8 kh, kl;
                unpack8(a0, a1, kh, kl);
                accS[mt] = MFMA_BF16(kl, Qh[s], accS[mt], 0, 0, 0);
                accS[mt] = MFMA_BF16(kh, Ql[s], accS[mt], 0, 0, 0);
                accS[mt] = MFMA_BF16(kh, Qh[s], accS[mt], 0, 0, 0);
            }
        }

        float tmax = -1e30f;
#pragma unroll
        for (int mt = 0; mt < 4; mt++)
#pragma unroll
            for (int r = 0; r < 4; r++) tmax = fmaxf(tmax, accS[mt][r]);
        tmax *= scale;
        tmax = fmaxf(tmax, __shfl_xor(tmax, 16));
        tmax = fmaxf(tmax, __shfl_xor(tmax, 32));
        float mnew = fmaxf(m_, tmax);
        float alpha = __expf(m_ - mnew);
        m_ = mnew;
        float rsum = 0.f;
#pragma unroll
        for (int mt = 0; mt < 4; mt++)
#pragma unroll
            for (int r = 0; r < 4; r++) {
                float p = __expf(accS[mt][r] * scale - mnew);
                sP[prow + 16 * mt + 4 * quad + r] = p;
                rsum += p;
            }
        rsum += __shfl_xor(rsum, 16);
        rsum += __shfl_xor(rsum, 32);
        l_ = l_ * alpha + rsum;

        float ar[4];
#pragma unroll
        for (int r = 0; r < 4; r++) ar[r] = __shfl(alpha, (quad << 2) + r);
#pragma unroll
        for (int nt = 0; nt < 4; nt++) {
#pragma unroll
            for (int r = 0; r < 4; r++) O0a[nt][r] *= ar[r];
            if constexpr (NV == 2)
#pragma unroll
                for (int r = 0; r < 4; r++) O1a[nt][r] *= ar[r];
        }

        short8 Ph[2], Pl[2];
#pragma unroll
        for (int s = 0; s < 2; s++) {
            float pv[8];
#pragma unroll
            for (int jj = 0; jj < 8; jj++)
                pv[jj] = sP[prow + 32 * s + 8 * quad + jj];
            split8(pv, Ph[s], Pl[s]);
        }

#pragma unroll
        for (int s = 0; s < 2; s++) {
#pragma unroll
            for (int nt = 0; nt < 4; nt++) {
                int d = 16 * nt + n;
                int base = d * 64;
                int c0 = 8 * s + 2 * quad;
                int sw = d & 15;
                uint4 b0 = *(const uint4*)&sV0[base + ((c0 ^ sw) << 2)];
                uint4 b1 = *(const uint4*)&sV0[base + (((c0 + 1) ^ sw) << 2)];
                short8 vh, vl;
                unpack8(b0, b1, vh, vl);
                O0a[nt] = MFMA_BF16(Pl[s], vh, O0a[nt], 0, 0, 0);
                O0a[nt] = MFMA_BF16(Ph[s], vl, O0a[nt], 0, 0, 0);
                O0a[nt] = MFMA_BF16(Ph[s], vh, O0a[nt], 0, 0, 0);
                if constexpr (NV == 2) {
                    uint4 c0v = *(const uint4*)&sV1[base + ((c0 ^ sw) << 2)];
                    uint4 c1v = *(const uint4*)&sV1[base + (((c0 + 1) ^ sw) << 2)];
                    short8 wh, wl;
                    unpack8(c0v, c1v, wh, wl);
                    O1a[nt] = MFMA_BF16(Pl[s], wh, O1a[nt], 0, 0, 0);
                    O1a[nt] = MFMA_BF16(Ph[s], wl, O1a[nt], 0, 0, 0);
                    O1a[nt] = MFMA_BF16(Ph[s], wh, O1a[nt], 0, 0, 0);
                }
            }
        }
    }

    float linv[4];
#pragma unroll
    for (int r = 0; r < 4; r++) linv[r] = 1.0f / __shfl(l_, (quad << 2) + r);
#pragma unroll
    for (int r = 0; r < 4; r++) {
        int row = i0 + 16 * w + 4 * quad + r;
#pragma unroll
        for (int nt = 0; nt < 4; nt++) {
            int col = 16 * nt + n;
            float v = O0a[nt][r] * linv[r];
            if constexpr (RESID) v += V0g[(size_t)row * v_sr + col];
            if constexpr (PACKO)
                ((unsigned int*)O0g)[(size_t)row * o_sr + col] = packsplit(v);
            else
                O0g[(size_t)row * o_sr + col] = v;
            if constexpr (NV == 2) {
                float v1 = O1a[nt][r] * linv[r];
                if constexpr (RESID) v1 += V1g[(size_t)row * v_sr + col];
                if constexpr (PACKO)
                    ((unsigned int*)O1g)[(size_t)row * o_sr + col] = packsplit(v1);
                else
                    O1g[(size_t)row * o_sr + col] = v1;
            }
        }
    }
}

// ---------------------------------------------------------------------------
extern "C" void kernel_launch(void* const* d_in, const int* in_sizes, int n_in,
                              void* d_out, int out_size, void* d_ws, size_t ws_size,
                              hipStream_t stream)
{
    const float* x1    = (const float*)d_in[0];
    const float* x2    = (const float*)d_in[1];
    const float* Wqkv1 = (const float*)d_in[2];
    const float* Wqkv2 = (const float*)d_in[3];
    const float* Wout1 = (const float*)d_in[4];
    const float* bout1 = (const float*)d_in[5];
    const float* Wout2 = (const float*)d_in[6];
    const float* bout2 = (const float*)d_in[7];
    const float* convw = (const float*)d_in[8];
    const float* convb = (const float*)d_in[9];

    const size_t QKV_ELEMS = (size_t)M_ * QKVC;
    const size_t BND_ELEMS = (size_t)M_ * INNER_;
    if (ws_size < (2 * QKV_ELEMS + 5 * BND_ELEMS) * sizeof(float)) return;

    float* ws   = (float*)d_ws;
    float* qkv1 = ws;
    float* qkv2 = qkv1 + QKV_ELEMS;
    float* MSg  = qkv2 + QKV_ELEMS;
    float* u1   = MSg + BND_ELEMS;
    float* u2   = u1 + BND_ELEMS;
    float* t1m  = u2 + BND_ELEMS;
    float* t2m  = t1m + BND_ELEMS;

    // Aliased packed buffers (time-disjoint usage):
    unsigned int* x1p  = (unsigned int*)t1m;        // consumed by QKV gemm (step 1)
    unsigned int* x2p  = (unsigned int*)t2m;
    unsigned int* w1pt = (unsigned int*)u2;         // consumed by QKV gemm (step 1)
    unsigned int* w2pt = w1pt + (size_t)QKVC * DIM_;
    unsigned int* wo1pt = (unsigned int*)u1;        // packed after u1's last read
    unsigned int* wo2pt = wo1pt + (size_t)DIM_ * DIM_;

    dim3 blk(256);

    // 0) pack activations + qkv weights
    pack_f32<<<dim3(M_ * DIM_ / 1024), blk, 0, stream>>>(x1, x1p);
    pack_f32<<<dim3(M_ * DIM_ / 1024), blk, 0, stream>>>(x2, x2p);
    pack_wt<<<dim3(QKVC / 256, DIM_ / 4), blk, 0, stream>>>(Wqkv1, w1pt, QKVC);
    pack_wt<<<dim3(QKVC / 256, DIM_ / 4), blk, 0, stream>>>(Wqkv2, w2pt, QKVC);

    // 1) QKV projections (MFMA)
    gemm_mfma<false><<<dim3(QKVC / 128, M_ / 128), blk, 0, stream>>>(
        x1p, w1pt, nullptr, qkv1, M_, QKVC);
    gemm_mfma<false><<<dim3(QKVC / 128, M_ / 128), blk, 0, stream>>>(
        x2p, w2pt, nullptr, qkv2, M_, QKVC);

    // 2) conv + sigmoid gate -> MSg
    convgate_kernel<<<dim3(M_), dim3(128), 0, stream>>>(qkv1, qkv2, convw, convb, MSg);

    // Stride descriptors
    const long long msg_sb = (long long)N_ * INNER_, msg_sh = HD_;
    const int       msg_sr = INNER_;
    const long long qkv_sb = (long long)N_ * QKVC, qkv_sh = HD_;
    const int       qkv_sr = QKVC;
    const long long u_sb = (long long)H_ * N_ * HD_, u_sh = (long long)N_ * HD_;
    const int       u_sr = HD_;

    // 3) Attention A (writes u1,u2 f32; overwrites w-packs in u2 - already used)
    mattn_kernel<2, true, false><<<dim3(N_ / 64, B_ * H_), blk, 0, stream>>>(
        MSg, msg_sb, msg_sh, msg_sr,
        MSg, msg_sb, msg_sh, msg_sr,
        qkv1 + 2 * INNER_, qkv2 + 2 * INNER_, qkv_sb, qkv_sh, qkv_sr,
        u1, u2, u_sb, u_sh, u_sr);

    // 4) Attention B -> packed t1m/t2m (overwrites x-packs - already used)
    mattn_kernel<1, false, true><<<dim3(N_ / 64, B_ * H_), blk, 0, stream>>>(
        qkv1, qkv_sb, qkv_sh, qkv_sr,
        qkv1 + INNER_, qkv_sb, qkv_sh, qkv_sr,
        u1, nullptr, u_sb, u_sh, u_sr,
        t1m, nullptr, msg_sb, msg_sh, msg_sr);
    mattn_kernel<1, false, true><<<dim3(N_ / 64, B_ * H_), blk, 0, stream>>>(
        qkv2, qkv_sb, qkv_sh, qkv_sr,
        qkv2 + INNER_, qkv_sb, qkv_sh, qkv_sr,
        u2, nullptr, u_sb, u_sh, u_sr,
        t2m, nullptr, msg_sb, msg_sh, msg_sr);

    // 4.5) pack output weights into u1 (u1's last reader was step 4a)
    pack_wt<<<dim3(DIM_ / 256, DIM_ / 4), blk, 0, stream>>>(Wout1, wo1pt, DIM_);
    pack_wt<<<dim3(DIM_ / 256, DIM_ / 4), blk, 0, stream>>>(Wout2, wo2pt, DIM_);

    // 5) Output projections (MFMA, bias, f32 out)
    float* out1 = (float*)d_out;
    float* out2 = out1 + (size_t)M_ * DIM_;
    gemm_mfma<true><<<dim3(DIM_ / 128, M_ / 128), blk, 0, stream>>>(
        (const unsigned int*)t1m, wo1pt, bout1, out1, M_, DIM_);
    gemm_mfma<true><<<dim3(DIM_ / 128, M_ / 128), blk, 0, stream>>>(
        (const unsigned int*)t2m, wo2pt, bout2, out2, M_, DIM_);
}

// Round 6
// 563.244 us; speedup vs baseline: 5.7039x; 1.4732x over previous
//
#include <hip/hip_runtime.h>
#include <hip/hip_bf16.h>

// Problem constants
#define B_     8
#define N_     1024
#define DIM_   512
#define H_     8
#define HD_    64
#define INNER_ 512
#define QKVC   2048   // 4*INNER
#define M_     8192   // B*N

typedef __attribute__((ext_vector_type(8))) short short8;
typedef __attribute__((ext_vector_type(4))) float f32x4;
#define MFMA_BF16 __builtin_amdgcn_mfma_f32_16x16x32_bf16

__device__ __forceinline__ unsigned short f2b(float x) {
    __hip_bfloat16 h = __float2bfloat16(x);
    unsigned short u; __builtin_memcpy(&u, &h, 2); return u;
}
// pack bf16 hi/lo split of x into one u32: (hi<<16)|lo
__device__ __forceinline__ unsigned int packsplit(float x) {
    unsigned int hb = f2b(x);
    float fh = __uint_as_float(hb << 16);
    unsigned int lb = f2b(x - fh);
    return (hb << 16) | lb;
}
__device__ __forceinline__ void split8(const float* v, short8& h, short8& l) {
#pragma unroll
    for (int i = 0; i < 8; i++) {
        unsigned int hb = f2b(v[i]);
        float fh = __uint_as_float(hb << 16);
        h[i] = (short)hb; l[i] = (short)f2b(v[i] - fh);
    }
}

// ---------------------------------------------------------------------------
// Pack kernels: f32 -> u32 (bf16hi<<16 | bf16lo)
// ---------------------------------------------------------------------------
__global__ __launch_bounds__(256)
void pack_f32(const float* __restrict__ in, unsigned int* __restrict__ out)
{
    size_t i = ((size_t)blockIdx.x * 256 + threadIdx.x) * 4;
    float4 v = *(const float4*)(in + i);
    uint4 p;
    p.x = packsplit(v.x); p.y = packsplit(v.y);
    p.z = packsplit(v.z); p.w = packsplit(v.w);
    *(uint4*)(out + i) = p;
}

// W[k][n] (f32, K=512 rows, N cols) -> Wt[n][k] packed u32
__global__ __launch_bounds__(256)
void pack_wt(const float* __restrict__ W, unsigned int* __restrict__ Wt, int N)
{
    const int n = blockIdx.x * 256 + threadIdx.x;
    const int k0 = blockIdx.y * 4;
    uint4 p;
    p.x = packsplit(W[(size_t)(k0 + 0) * N + n]);
    p.y = packsplit(W[(size_t)(k0 + 1) * N + n]);
    p.z = packsplit(W[(size_t)(k0 + 2) * N + n]);
    p.w = packsplit(W[(size_t)(k0 + 3) * N + n]);
    *(uint4*)&Wt[(size_t)n * 512 + k0] = p;
}

// ---------------------------------------------------------------------------
// MFMA GEMM with bf16 hi/lo split (3 MFMA per product), K fixed = 512.
// A: packed u32 [M][512]. Bt: packed u32 [N][512]. C: f32 (+bias).
// PACKK: output cols [512,1024) are stored packed-u32 in place (qkv k-slice,
// consumed only as attention-K).
// ---------------------------------------------------------------------------
template<bool BIAS, bool PACKK>
__global__ __launch_bounds__(256)
void gemm_mfma(const unsigned int* __restrict__ Ap, const unsigned int* __restrict__ Btp,
               const float* __restrict__ bias, float* __restrict__ Cp,
               int M, int N)
{
    const int K = 512;
    __shared__ __align__(16) unsigned short sA[128 * 64];
    __shared__ __align__(16) unsigned short sB[128 * 64];

    const int t    = threadIdx.x;
    const int lane = t & 63;
    const int w    = t >> 6;
    const int n16  = lane & 15, quad = lane >> 4;
    const int wm   = w >> 1, wn = w & 1;
    const int m0 = blockIdx.y * 128, n0 = blockIdx.x * 128;

    f32x4 acc[4][4];
#pragma unroll
    for (int mt = 0; mt < 4; mt++)
#pragma unroll
        for (int nt = 0; nt < 4; nt++) acc[mt][nt] = (f32x4){0.f, 0.f, 0.f, 0.f};

    const int srow = t >> 1;
    const int kb   = (t & 1) * 16;
    const unsigned int* ag = Ap  + (size_t)(m0 + srow) * K + kb;
    const unsigned int* bg = Btp + (size_t)(n0 + srow) * K + kb;
    const int s7s = srow & 7;
    unsigned short* swA = &sA[srow * 64];
    unsigned short* swB = &sB[srow * 64];

    for (int k0 = 0; k0 < K; k0 += 32) {
        __syncthreads();
#pragma unroll
        for (int i = 0; i < 4; i++) {
            const int kk = kb + i * 4;
            const int ch = kk >> 3;
            const int ho = kk & 4;
            const int c_hi = ((ch    ) ^ s7s) << 3;
            const int c_lo = ((ch + 4) ^ s7s) << 3;
            uint4 va = *(const uint4*)(ag + k0 + i * 4);
            uint4 vb = *(const uint4*)(bg + k0 + i * 4);
            uint2 ha, la, hb, lb;
            ha.x = (va.y & 0xFFFF0000u) | (va.x >> 16);
            ha.y = (va.w & 0xFFFF0000u) | (va.z >> 16);
            la.x = (va.y << 16) | (va.x & 0xFFFFu);
            la.y = (va.w << 16) | (va.z & 0xFFFFu);
            hb.x = (vb.y & 0xFFFF0000u) | (vb.x >> 16);
            hb.y = (vb.w & 0xFFFF0000u) | (vb.z >> 16);
            lb.x = (vb.y << 16) | (vb.x & 0xFFFFu);
            lb.y = (vb.w << 16) | (vb.z & 0xFFFFu);
            *(uint2*)&swA[c_hi + ho] = ha;
            *(uint2*)&swA[c_lo + ho] = la;
            *(uint2*)&swB[c_hi + ho] = hb;
            *(uint2*)&swB[c_lo + ho] = lb;
        }
        __syncthreads();

        short8 Ah[4], Al[4];
#pragma unroll
        for (int mt = 0; mt < 4; mt++) {
            const int row = 64 * wm + 16 * mt + n16;
            const int base = row * 64;
            const int s7 = row & 7;
            Ah[mt] = *(const short8*)&sA[base + (((quad    ) ^ s7) << 3)];
            Al[mt] = *(const short8*)&sA[base + (((quad + 4) ^ s7) << 3)];
        }
#pragma unroll
        for (int nt = 0; nt < 4; nt++) {
            const int row = 64 * wn + 16 * nt + n16;
            const int base = row * 64;
            const int s7 = row & 7;
            short8 Bh = *(const short8*)&sB[base + (((quad    ) ^ s7) << 3)];
            short8 Bl = *(const short8*)&sB[base + (((quad + 4) ^ s7) << 3)];
#pragma unroll
            for (int mt = 0; mt < 4; mt++) {
                acc[mt][nt] = MFMA_BF16(Ah[mt], Bh, acc[mt][nt], 0, 0, 0);
                acc[mt][nt] = MFMA_BF16(Al[mt], Bh, acc[mt][nt], 0, 0, 0);
                acc[mt][nt] = MFMA_BF16(Ah[mt], Bl, acc[mt][nt], 0, 0, 0);
            }
        }
    }

    const bool packout = PACKK && ((n0 >> 9) == 1);   // qkv k-slice cols
    float bv[4];
#pragma unroll
    for (int nt = 0; nt < 4; nt++)
        bv[nt] = BIAS ? bias[n0 + 64 * wn + 16 * nt + n16] : 0.f;
#pragma unroll
    for (int mt = 0; mt < 4; mt++) {
        const int rbase = m0 + 64 * wm + 16 * mt + 4 * quad;
#pragma unroll
        for (int r = 0; r < 4; r++) {
#pragma unroll
            for (int nt = 0; nt < 4; nt++) {
                const int col = n0 + 64 * wn + 16 * nt + n16;
                const size_t off = (size_t)(rbase + r) * N + col;
                const float v = acc[mt][nt][r] + bv[nt];
                if (packout) ((unsigned int*)Cp)[off] = packsplit(v);
                else         Cp[off] = v;
            }
        }
    }
}

// ---------------------------------------------------------------------------
// Depthwise conv (k=5, pad=2) + sigmoid gate. Writes MSg (f32, attention-Q)
// and MSgp (packed u32, attention-K).
// ---------------------------------------------------------------------------
__global__ __launch_bounds__(128)
void convgate_kernel(const float* __restrict__ qkv1, const float* __restrict__ qkv2,
                     const float* __restrict__ convw,
                     const float* __restrict__ convb,
                     float* __restrict__ MSg, unsigned int* __restrict__ MSgp)
{
    __shared__ float ms[INNER_];
    const int blk = blockIdx.x;
    const int n = blk & (N_ - 1);
    const int t = threadIdx.x;

    const float4* q1 = (const float4*)(qkv1 + (size_t)blk * QKVC + 3 * INNER_);
    const float4* q2 = (const float4*)(qkv2 + (size_t)blk * QKVC + 3 * INNER_);
    float4 v1 = q1[t], v2 = q2[t];
    float4 s;
    s.x = v1.x + v2.x; s.y = v1.y + v2.y; s.z = v1.z + v2.z; s.w = v1.w + v2.w;
    *(float4*)&ms[t * 4] = s;
    __syncthreads();

    float w[5];
#pragma unroll
    for (int k = 0; k < 5; k++) w[k] = convw[n * 5 + k];
    const float cb = convb[n];

    float out[4];
#pragma unroll
    for (int ff = 0; ff < 4; ff++) {
        int f = t * 4 + ff;
        float A = cb;
#pragma unroll
        for (int k = 0; k < 5; k++) {
            int idx = f + k - 2;
            if (idx >= 0 && idx < INNER_) A += ms[idx] * w[k];
        }
        float sg = 1.f / (1.f + __expf(-A));
        out[ff] = ms[f] * sg;
    }
    *(float4*)&MSg[(size_t)blk * INNER_ + t * 4] = make_float4(out[0], out[1], out[2], out[3]);
    uint4 p;
    p.x = packsplit(out[0]); p.y = packsplit(out[1]);
    p.z = packsplit(out[2]); p.w = packsplit(out[3]);
    *(uint4*)&MSgp[(size_t)blk * INNER_ + t * 4] = p;
}

// ---------------------------------------------------------------------------
// MFMA flash attention, v2. Q f32 (split to persistent frags). K pre-packed
// u32 -> staged as hi/lo ushort PLANES (XOR-swizzled 16B chunks): QK frags
// are direct ds_read_b128, zero unpack. V, P plain bf16 (1 MFMA each);
// V transposed at staging via j-pair u32 writes; P wave-local (no barrier).
// ---------------------------------------------------------------------------
template<int NV, bool RESID, bool PACKO>
__global__ __launch_bounds__(256)
void mattn_kernel(const float* __restrict__ Qb, long long q_sb, long long q_sh, int q_sr,
                  const unsigned int* __restrict__ Kb, long long k_sb, long long k_sh, int k_sr,
                  const float* __restrict__ V0b, const float* __restrict__ V1b,
                  long long v_sb, long long v_sh, int v_sr,
                  float* __restrict__ O0b, float* __restrict__ O1b,
                  long long o_sb, long long o_sh, int o_sr)
{
    __shared__ __align__(16) unsigned short sK[64 * 128];   // hi|lo chunk-16 planes
    __shared__ __align__(16) unsigned short sV0[64 * 64];   // V^T plain bf16
    __shared__ __align__(16) unsigned short sV1[(NV == 2) ? 64 * 64 : 8];
    __shared__ __align__(16) unsigned short sP[64 * 64];    // P plain bf16

    const int t    = threadIdx.x;
    const int w    = t >> 6;
    const int lane = t & 63;
    const int n16  = lane & 15;
    const int quad = lane >> 4;

    const int bh = blockIdx.y;
    const int b  = bh >> 3, h = bh & 7;
    const int i0 = blockIdx.x * 64;

    const float* Qg         = Qb  + (size_t)b * q_sb + (size_t)h * q_sh;
    const unsigned int* Kg  = Kb  + (size_t)b * k_sb + (size_t)h * k_sh;
    const float* V0g        = V0b + (size_t)b * v_sb + (size_t)h * v_sh;
    const float* V1g = (NV == 2) ? (V1b + (size_t)b * v_sb + (size_t)h * v_sh) : nullptr;
    float* O0g = O0b + (size_t)b * o_sb + (size_t)h * o_sh;
    float* O1g = (NV == 2) ? (O1b + (size_t)b * o_sb + (size_t)h * o_sh) : nullptr;

    // persistent Q fragments (hi/lo split)
    short8 Qh[2], Ql[2];
#pragma unroll
    for (int s = 0; s < 2; s++) {
        const float* qp = Qg + (size_t)(i0 + 16 * w + n16) * q_sr + 32 * s + 8 * quad;
        float qv[8];
        float4 q0 = *(const float4*)qp;
        float4 q1 = *(const float4*)(qp + 4);
        qv[0]=q0.x; qv[1]=q0.y; qv[2]=q0.z; qv[3]=q0.w;
        qv[4]=q1.x; qv[5]=q1.y; qv[6]=q1.z; qv[7]=q1.w;
        split8(qv, Qh[s], Ql[s]);
    }

    float m_ = -1e30f, l_ = 0.f;
    f32x4 O0a[4], O1a[(NV == 2) ? 4 : 1];
#pragma unroll
    for (int nt = 0; nt < 4; nt++) O0a[nt] = (f32x4){0.f,0.f,0.f,0.f};
    if constexpr (NV == 2) {
#pragma unroll
        for (int nt = 0; nt < 4; nt++) O1a[nt] = (f32x4){0.f,0.f,0.f,0.f};
    }

    const float scale = 0.125f;
    const int prow = 16 * w + n16;
    const int krow = t >> 3, kfc = t & 7;     // K staging: row chunk-of-8
    const int vc = t & 15, vp0 = t >> 4;      // V staging: d-chunk, j-pair

    for (int j0 = 0; j0 < N_; j0 += 64) {
        __syncthreads();

        // ---- stage K (packed u32 source -> hi/lo planes, byte split only)
#pragma unroll
        for (int it = 0; it < 2; it++) {
            const int row = krow + 32 * it;
            const unsigned int* kp = Kg + (size_t)(j0 + row) * k_sr + 8 * kfc;
            uint4 va = *(const uint4*)kp;
            uint4 vb = *(const uint4*)(kp + 4);
            uint4 hi, lo;
            hi.x = (va.x >> 16) | (va.y & 0xFFFF0000u);
            hi.y = (va.z >> 16) | (va.w & 0xFFFF0000u);
            hi.z = (vb.x >> 16) | (vb.y & 0xFFFF0000u);
            hi.w = (vb.z >> 16) | (vb.w & 0xFFFF0000u);
            lo.x = (va.x & 0xFFFFu) | (va.y << 16);
            lo.y = (va.z & 0xFFFFu) | (va.w << 16);
            lo.z = (vb.x & 0xFFFFu) | (vb.y << 16);
            lo.w = (vb.z & 0xFFFFu) | (vb.w << 16);
            const int r15 = row & 15;
            *(uint4*)&sK[row * 128 + (((kfc    ) ^ r15) << 3)] = hi;
            *(uint4*)&sK[row * 128 + (((kfc + 8) ^ r15) << 3)] = lo;
        }
        // ---- stage V transposed, plain bf16, j-pair u32 writes
#pragma unroll
        for (int it = 0; it < 2; it++) {
            const int p = vp0 + 16 * it;
            const int j = 2 * p;
            const float* a0 = V0g + (size_t)(j0 + j) * v_sr + 4 * vc;
            float4 va = *(const float4*)a0;
            float4 vb = *(const float4*)(a0 + v_sr);
#pragma unroll
            for (int e = 0; e < 4; e++) {
                float fa = (e==0)?va.x:(e==1)?va.y:(e==2)?va.z:va.w;
                float fb = (e==0)?vb.x:(e==1)?vb.y:(e==2)?vb.z:vb.w;
                unsigned int u = (unsigned int)f2b(fa) | ((unsigned int)f2b(fb) << 16);
                const int d = 4 * vc + e;
                const int phys = (p >> 2) ^ ((d ^ (d >> 2)) & 7);
                *(unsigned int*)&sV0[d * 64 + (phys << 3) + (j & 7)] = u;
            }
            if constexpr (NV == 2) {
                const float* a1 = V1g + (size_t)(j0 + j) * v_sr + 4 * vc;
                float4 wa = *(const float4*)a1;
                float4 wb = *(const float4*)(a1 + v_sr);
#pragma unroll
                for (int e = 0; e < 4; e++) {
                    float fa = (e==0)?wa.x:(e==1)?wa.y:(e==2)?wa.z:wa.w;
                    float fb = (e==0)?wb.x:(e==1)?wb.y:(e==2)?wb.z:wb.w;
                    unsigned int u = (unsigned int)f2b(fa) | ((unsigned int)f2b(fb) << 16);
                    const int d = 4 * vc + e;
                    const int phys = (p >> 2) ^ ((d ^ (d >> 2)) & 7);
                    *(unsigned int*)&sV1[d * 64 + (phys << 3) + (j & 7)] = u;
                }
            }
        }
        __syncthreads();

        // ---- S^T = K.Q^T, split 3-MFMA, frags straight from planes
        f32x4 accS[4];
#pragma unroll
        for (int mt = 0; mt < 4; mt++) accS[mt] = (f32x4){0.f,0.f,0.f,0.f};
#pragma unroll
        for (int s = 0; s < 2; s++) {
#pragma unroll
            for (int mt = 0; mt < 4; mt++) {
                const unsigned short* kb2 = &sK[(16 * mt + n16) * 128];
                short8 kh = *(const short8*)&kb2[(((4*s + quad)    ) ^ n16) << 3];
                short8 kl = *(const short8*)&kb2[(((4*s + quad) + 8) ^ n16) << 3];
                accS[mt] = MFMA_BF16(kl, Qh[s], accS[mt], 0, 0, 0);
                accS[mt] = MFMA_BF16(kh, Ql[s], accS[mt], 0, 0, 0);
                accS[mt] = MFMA_BF16(kh, Qh[s], accS[mt], 0, 0, 0);
            }
        }

        // ---- online softmax; P written bf16, wave-local (no barrier)
        float tmax = -1e30f;
#pragma unroll
        for (int mt = 0; mt < 4; mt++)
#pragma unroll
            for (int r = 0; r < 4; r++) tmax = fmaxf(tmax, accS[mt][r]);
        tmax *= scale;
        tmax = fmaxf(tmax, __shfl_xor(tmax, 16));
        tmax = fmaxf(tmax, __shfl_xor(tmax, 32));
        const float mnew = fmaxf(m_, tmax);
        const float alpha = __expf(m_ - mnew);
        m_ = mnew;
        float rsum = 0.f;
#pragma unroll
        for (int mt = 0; mt < 4; mt++) {
            float p0 = __expf(accS[mt][0] * scale - mnew);
            float p1 = __expf(accS[mt][1] * scale - mnew);
            float p2 = __expf(accS[mt][2] * scale - mnew);
            float p3 = __expf(accS[mt][3] * scale - mnew);
            rsum += (p0 + p1) + (p2 + p3);
            uint2 u;
            u.x = (unsigned int)f2b(p0) | ((unsigned int)f2b(p1) << 16);
            u.y = (unsigned int)f2b(p2) | ((unsigned int)f2b(p3) << 16);
            const int phys = (2 * mt + (quad >> 1)) ^ (n16 & 7);
            *(uint2*)&sP[prow * 64 + (phys << 3) + 4 * (quad & 1)] = u;
        }
        rsum += __shfl_xor(rsum, 16);
        rsum += __shfl_xor(rsum, 32);
        l_ = l_ * alpha + rsum;

        float ar[4];
#pragma unroll
        for (int r = 0; r < 4; r++) ar[r] = __shfl(alpha, (quad << 2) + r);
#pragma unroll
        for (int nt = 0; nt < 4; nt++) {
#pragma unroll
            for (int r = 0; r < 4; r++) O0a[nt][r] *= ar[r];
            if constexpr (NV == 2)
#pragma unroll
                for (int r = 0; r < 4; r++) O1a[nt][r] *= ar[r];
        }

        // ---- PV: plain bf16, 1 MFMA per fragment
#pragma unroll
        for (int s = 0; s < 2; s++) {
            short8 Pf = *(const short8*)&sP[prow * 64 + (((4*s + quad) ^ (n16 & 7)) << 3)];
#pragma unroll
            for (int nt = 0; nt < 4; nt++) {
                const int d = 16 * nt + n16;
                const int phys = (4*s + quad) ^ ((d ^ (d >> 2)) & 7);
                short8 vf = *(const short8*)&sV0[d * 64 + (phys << 3)];
                O0a[nt] = MFMA_BF16(Pf, vf, O0a[nt], 0, 0, 0);
                if constexpr (NV == 2) {
                    short8 vf1 = *(const short8*)&sV1[d * 64 + (phys << 3)];
                    O1a[nt] = MFMA_BF16(Pf, vf1, O1a[nt], 0, 0, 0);
                }
            }
        }
    }

    // ---- epilogue
    float linv[4];
#pragma unroll
    for (int r = 0; r < 4; r++) linv[r] = 1.0f / __shfl(l_, (quad << 2) + r);
#pragma unroll
    for (int r = 0; r < 4; r++) {
        const int row = i0 + 16 * w + 4 * quad + r;
#pragma unroll
        for (int nt = 0; nt < 4; nt++) {
            const int col = 16 * nt + n16;
            float v = O0a[nt][r] * linv[r];
            if constexpr (RESID) v += V0g[(size_t)row * v_sr + col];
            if constexpr (PACKO)
                ((unsigned int*)O0g)[(size_t)row * o_sr + col] = packsplit(v);
            else
                O0g[(size_t)row * o_sr + col] = v;
            if constexpr (NV == 2) {
                float v1 = O1a[nt][r] * linv[r];
                if constexpr (RESID) v1 += V1g[(size_t)row * v_sr + col];
                if constexpr (PACKO)
                    ((unsigned int*)O1g)[(size_t)row * o_sr + col] = packsplit(v1);
                else
                    O1g[(size_t)row * o_sr + col] = v1;
            }
        }
    }
}

// ---------------------------------------------------------------------------
extern "C" void kernel_launch(void* const* d_in, const int* in_sizes, int n_in,
                              void* d_out, int out_size, void* d_ws, size_t ws_size,
                              hipStream_t stream)
{
    const float* x1    = (const float*)d_in[0];
    const float* x2    = (const float*)d_in[1];
    const float* Wqkv1 = (const float*)d_in[2];
    const float* Wqkv2 = (const float*)d_in[3];
    const float* Wout1 = (const float*)d_in[4];
    const float* bout1 = (const float*)d_in[5];
    const float* Wout2 = (const float*)d_in[6];
    const float* bout2 = (const float*)d_in[7];
    const float* convw = (const float*)d_in[8];
    const float* convb = (const float*)d_in[9];

    const size_t QKV_ELEMS = (size_t)M_ * QKVC;
    const size_t BND_ELEMS = (size_t)M_ * INNER_;
    if (ws_size < (2 * QKV_ELEMS + 5 * BND_ELEMS) * sizeof(float)) return;

    float* ws   = (float*)d_ws;
    float* qkv1 = ws;
    float* qkv2 = qkv1 + QKV_ELEMS;
    float* MSg  = qkv2 + QKV_ELEMS;
    float* u1   = MSg + BND_ELEMS;
    float* u2   = u1 + BND_ELEMS;
    float* t1m  = u2 + BND_ELEMS;
    float* t2m  = t1m + BND_ELEMS;

    // Aliased packed buffers (time-disjoint):
    unsigned int* x1p   = (unsigned int*)t1m;     // consumed step 1
    unsigned int* x2p   = (unsigned int*)t2m;     // consumed step 1
    unsigned int* MSgp  = (unsigned int*)t1m;     // written step 2, read step 3 (pre attn-B)
    unsigned int* w1pt  = (unsigned int*)u2;      // consumed step 1
    unsigned int* w2pt  = w1pt + (size_t)QKVC * DIM_;
    unsigned int* wo1pt = (unsigned int*)u1;      // packed after u1's last read
    unsigned int* wo2pt = wo1pt + (size_t)DIM_ * DIM_;

    dim3 blk(256);

    // 0) pack activations + qkv weights
    pack_f32<<<dim3(M_ * DIM_ / 1024), blk, 0, stream>>>(x1, x1p);
    pack_f32<<<dim3(M_ * DIM_ / 1024), blk, 0, stream>>>(x2, x2p);
    pack_wt<<<dim3(QKVC / 256, DIM_ / 4), blk, 0, stream>>>(Wqkv1, w1pt, QKVC);
    pack_wt<<<dim3(QKVC / 256, DIM_ / 4), blk, 0, stream>>>(Wqkv2, w2pt, QKVC);

    // 1) QKV projections (MFMA); k-slice cols [512,1024) written packed in place
    gemm_mfma<false, true><<<dim3(QKVC / 128, M_ / 128), blk, 0, stream>>>(
        x1p, w1pt, nullptr, qkv1, M_, QKVC);
    gemm_mfma<false, true><<<dim3(QKVC / 128, M_ / 128), blk, 0, stream>>>(
        x2p, w2pt, nullptr, qkv2, M_, QKVC);

    // 2) conv + sigmoid gate -> MSg (f32) + MSgp (packed)
    convgate_kernel<<<dim3(M_), dim3(128), 0, stream>>>(qkv1, qkv2, convw, convb, MSg, MSgp);

    // Stride descriptors
    const long long msg_sb = (long long)N_ * INNER_, msg_sh = HD_;
    const int       msg_sr = INNER_;
    const long long qkv_sb = (long long)N_ * QKVC, qkv_sh = HD_;
    const int       qkv_sr = QKVC;
    const long long u_sb = (long long)H_ * N_ * HD_, u_sh = (long long)N_ * HD_;
    const int       u_sr = HD_;

    // 3) Attention A: K = MSgp (packed), Q = MSg f32, V = v-slices, +resid
    mattn_kernel<2, true, false><<<dim3(N_ / 64, B_ * H_), blk, 0, stream>>>(
        MSg, msg_sb, msg_sh, msg_sr,
        MSgp, msg_sb, msg_sh, msg_sr,
        qkv1 + 2 * INNER_, qkv2 + 2 * INNER_, qkv_sb, qkv_sh, qkv_sr,
        u1, u2, u_sb, u_sh, u_sr);

    // 4) Attention B: K = qkv k-slice (packed in place), V = u, out packed t
    mattn_kernel<1, false, true><<<dim3(N_ / 64, B_ * H_), blk, 0, stream>>>(
        qkv1, qkv_sb, qkv_sh, qkv_sr,
        (const unsigned int*)qkv1 + INNER_, qkv_sb, qkv_sh, qkv_sr,
        u1, nullptr, u_sb, u_sh, u_sr,
        t1m, nullptr, msg_sb, msg_sh, msg_sr);
    mattn_kernel<1, false, true><<<dim3(N_ / 64, B_ * H_), blk, 0, stream>>>(
        qkv2, qkv_sb, qkv_sh, qkv_sr,
        (const unsigned int*)qkv2 + INNER_, qkv_sb, qkv_sh, qkv_sr,
        u2, nullptr, u_sb, u_sh, u_sr,
        t2m, nullptr, msg_sb, msg_sh, msg_sr);

    // 4.5) pack output weights into u1 (u1's last reader was step 4a)
    pack_wt<<<dim3(DIM_ / 256, DIM_ / 4), blk, 0, stream>>>(Wout1, wo1pt, DIM_);
    pack_wt<<<dim3(DIM_ / 256, DIM_ / 4), blk, 0, stream>>>(Wout2, wo2pt, DIM_);

    // 5) Output projections (MFMA, bias, f32 out)
    float* out1 = (float*)d_out;
    float* out2 = out1 + (size_t)M_ * DIM_;
    gemm_mfma<true, false><<<dim3(DIM_ / 128, M_ / 128), blk, 0, stream>>>(
        (const unsigned int*)t1m, wo1pt, bout1, out1, M_, DIM_);
    gemm_mfma<true, false><<<dim3(DIM_ / 128, M_ / 128), blk, 0, stream>>>(
        (const unsigned int*)t2m, wo2pt, bout2, out2, M_, DIM_);
}

// Round 7
// 488.444 us; speedup vs baseline: 6.5774x; 1.1531x over previous
//
#include <hip/hip_runtime.h>
#include <hip/hip_bf16.h>

// Problem constants
#define B_     8
#define N_     1024
#define DIM_   512
#define H_     8
#define HD_    64
#define INNER_ 512
#define QKVC   2048   // 4*INNER
#define M_     8192   // B*N

typedef __attribute__((ext_vector_type(8))) short short8;
typedef __attribute__((ext_vector_type(4))) float f32x4;
#define MFMA_BF16 __builtin_amdgcn_mfma_f32_16x16x32_bf16

__device__ __forceinline__ unsigned short f2b(float x) {
    __hip_bfloat16 h = __float2bfloat16(x);
    unsigned short u; __builtin_memcpy(&u, &h, 2); return u;
}
// pack bf16 hi/lo split of x into one u32: (hi<<16)|lo
__device__ __forceinline__ unsigned int packsplit(float x) {
    unsigned int hb = f2b(x);
    float fh = __uint_as_float(hb << 16);
    unsigned int lb = f2b(x - fh);
    return (hb << 16) | lb;
}
__device__ __forceinline__ void split8(const float* v, short8& h, short8& l) {
#pragma unroll
    for (int i = 0; i < 8; i++) {
        unsigned int hb = f2b(v[i]);
        float fh = __uint_as_float(hb << 16);
        h[i] = (short)hb; l[i] = (short)f2b(v[i] - fh);
    }
}

// ---------------------------------------------------------------------------
// Pack kernels: f32 -> u32 (bf16hi<<16 | bf16lo)
// ---------------------------------------------------------------------------
__global__ __launch_bounds__(256)
void pack_f32(const float* __restrict__ in, unsigned int* __restrict__ out)
{
    size_t i = ((size_t)blockIdx.x * 256 + threadIdx.x) * 4;
    float4 v = *(const float4*)(in + i);
    uint4 p;
    p.x = packsplit(v.x); p.y = packsplit(v.y);
    p.z = packsplit(v.z); p.w = packsplit(v.w);
    *(uint4*)(out + i) = p;
}

// W[k][n] (f32, K=512 rows, N cols) -> Wt[n][k] packed u32
__global__ __launch_bounds__(256)
void pack_wt(const float* __restrict__ W, unsigned int* __restrict__ Wt, int N)
{
    const int n = blockIdx.x * 256 + threadIdx.x;
    const int k0 = blockIdx.y * 4;
    uint4 p;
    p.x = packsplit(W[(size_t)(k0 + 0) * N + n]);
    p.y = packsplit(W[(size_t)(k0 + 1) * N + n]);
    p.z = packsplit(W[(size_t)(k0 + 2) * N + n]);
    p.w = packsplit(W[(size_t)(k0 + 3) * N + n]);
    *(uint4*)&Wt[(size_t)n * 512 + k0] = p;
}

// ---------------------------------------------------------------------------
// MFMA GEMM with bf16 hi/lo split (3 MFMA per product), K fixed = 512.
// (unchanged from round 6)
// ---------------------------------------------------------------------------
template<bool BIAS, bool PACKK>
__global__ __launch_bounds__(256)
void gemm_mfma(const unsigned int* __restrict__ Ap, const unsigned int* __restrict__ Btp,
               const float* __restrict__ bias, float* __restrict__ Cp,
               int M, int N)
{
    const int K = 512;
    __shared__ __align__(16) unsigned short sA[128 * 64];
    __shared__ __align__(16) unsigned short sB[128 * 64];

    const int t    = threadIdx.x;
    const int lane = t & 63;
    const int w    = t >> 6;
    const int n16  = lane & 15, quad = lane >> 4;
    const int wm   = w >> 1, wn = w & 1;
    const int m0 = blockIdx.y * 128, n0 = blockIdx.x * 128;

    f32x4 acc[4][4];
#pragma unroll
    for (int mt = 0; mt < 4; mt++)
#pragma unroll
        for (int nt = 0; nt < 4; nt++) acc[mt][nt] = (f32x4){0.f, 0.f, 0.f, 0.f};

    const int srow = t >> 1;
    const int kb   = (t & 1) * 16;
    const unsigned int* ag = Ap  + (size_t)(m0 + srow) * K + kb;
    const unsigned int* bg = Btp + (size_t)(n0 + srow) * K + kb;
    const int s7s = srow & 7;
    unsigned short* swA = &sA[srow * 64];
    unsigned short* swB = &sB[srow * 64];

    for (int k0 = 0; k0 < K; k0 += 32) {
        __syncthreads();
#pragma unroll
        for (int i = 0; i < 4; i++) {
            const int kk = kb + i * 4;
            const int ch = kk >> 3;
            const int ho = kk & 4;
            const int c_hi = ((ch    ) ^ s7s) << 3;
            const int c_lo = ((ch + 4) ^ s7s) << 3;
            uint4 va = *(const uint4*)(ag + k0 + i * 4);
            uint4 vb = *(const uint4*)(bg + k0 + i * 4);
            uint2 ha, la, hb, lb;
            ha.x = (va.y & 0xFFFF0000u) | (va.x >> 16);
            ha.y = (va.w & 0xFFFF0000u) | (va.z >> 16);
            la.x = (va.y << 16) | (va.x & 0xFFFFu);
            la.y = (va.w << 16) | (va.z & 0xFFFFu);
            hb.x = (vb.y & 0xFFFF0000u) | (vb.x >> 16);
            hb.y = (vb.w & 0xFFFF0000u) | (vb.z >> 16);
            lb.x = (vb.y << 16) | (vb.x & 0xFFFFu);
            lb.y = (vb.w << 16) | (vb.z & 0xFFFFu);
            *(uint2*)&swA[c_hi + ho] = ha;
            *(uint2*)&swA[c_lo + ho] = la;
            *(uint2*)&swB[c_hi + ho] = hb;
            *(uint2*)&swB[c_lo + ho] = lb;
        }
        __syncthreads();

        short8 Ah[4], Al[4];
#pragma unroll
        for (int mt = 0; mt < 4; mt++) {
            const int row = 64 * wm + 16 * mt + n16;
            const int base = row * 64;
            const int s7 = row & 7;
            Ah[mt] = *(const short8*)&sA[base + (((quad    ) ^ s7) << 3)];
            Al[mt] = *(const short8*)&sA[base + (((quad + 4) ^ s7) << 3)];
        }
#pragma unroll
        for (int nt = 0; nt < 4; nt++) {
            const int row = 64 * wn + 16 * nt + n16;
            const int base = row * 64;
            const int s7 = row & 7;
            short8 Bh = *(const short8*)&sB[base + (((quad    ) ^ s7) << 3)];
            short8 Bl = *(const short8*)&sB[base + (((quad + 4) ^ s7) << 3)];
#pragma unroll
            for (int mt = 0; mt < 4; mt++) {
                acc[mt][nt] = MFMA_BF16(Ah[mt], Bh, acc[mt][nt], 0, 0, 0);
                acc[mt][nt] = MFMA_BF16(Al[mt], Bh, acc[mt][nt], 0, 0, 0);
                acc[mt][nt] = MFMA_BF16(Ah[mt], Bl, acc[mt][nt], 0, 0, 0);
            }
        }
    }

    const bool packout = PACKK && ((n0 >> 9) == 1);   // qkv k-slice cols
    float bv[4];
#pragma unroll
    for (int nt = 0; nt < 4; nt++)
        bv[nt] = BIAS ? bias[n0 + 64 * wn + 16 * nt + n16] : 0.f;
#pragma unroll
    for (int mt = 0; mt < 4; mt++) {
        const int rbase = m0 + 64 * wm + 16 * mt + 4 * quad;
#pragma unroll
        for (int r = 0; r < 4; r++) {
#pragma unroll
            for (int nt = 0; nt < 4; nt++) {
                const int col = n0 + 64 * wn + 16 * nt + n16;
                const size_t off = (size_t)(rbase + r) * N + col;
                const float v = acc[mt][nt][r] + bv[nt];
                if (packout) ((unsigned int*)Cp)[off] = packsplit(v);
                else         Cp[off] = v;
            }
        }
    }
}

// ---------------------------------------------------------------------------
// Depthwise conv (k=5, pad=2) + sigmoid gate. Writes MSg (f32) + MSgp (packed)
// ---------------------------------------------------------------------------
__global__ __launch_bounds__(128)
void convgate_kernel(const float* __restrict__ qkv1, const float* __restrict__ qkv2,
                     const float* __restrict__ convw,
                     const float* __restrict__ convb,
                     float* __restrict__ MSg, unsigned int* __restrict__ MSgp)
{
    __shared__ float ms[INNER_];
    const int blk = blockIdx.x;
    const int n = blk & (N_ - 1);
    const int t = threadIdx.x;

    const float4* q1 = (const float4*)(qkv1 + (size_t)blk * QKVC + 3 * INNER_);
    const float4* q2 = (const float4*)(qkv2 + (size_t)blk * QKVC + 3 * INNER_);
    float4 v1 = q1[t], v2 = q2[t];
    float4 s;
    s.x = v1.x + v2.x; s.y = v1.y + v2.y; s.z = v1.z + v2.z; s.w = v1.w + v2.w;
    *(float4*)&ms[t * 4] = s;
    __syncthreads();

    float w[5];
#pragma unroll
    for (int k = 0; k < 5; k++) w[k] = convw[n * 5 + k];
    const float cb = convb[n];

    float out[4];
#pragma unroll
    for (int ff = 0; ff < 4; ff++) {
        int f = t * 4 + ff;
        float A = cb;
#pragma unroll
        for (int k = 0; k < 5; k++) {
            int idx = f + k - 2;
            if (idx >= 0 && idx < INNER_) A += ms[idx] * w[k];
        }
        float sg = 1.f / (1.f + __expf(-A));
        out[ff] = ms[f] * sg;
    }
    *(float4*)&MSg[(size_t)blk * INNER_ + t * 4] = make_float4(out[0], out[1], out[2], out[3]);
    uint4 p;
    p.x = packsplit(out[0]); p.y = packsplit(out[1]);
    p.z = packsplit(out[2]); p.w = packsplit(out[3]);
    *(uint4*)&MSgp[(size_t)blk * INNER_ + t * 4] = p;
}

// ---------------------------------------------------------------------------
// MFMA flash attention v3: 512 threads, Q-tile 128 (per-wave code = v2).
// XCD swizzle: linear bid, c=bid&7 selects XCD (assumed bid%8); all 8 q-tiles
// of head hh=8g+c share XCD c -> K/V L2-resident. NPROB=2 merges two
// independent problems (attn-B pair) into one dispatch.
// ---------------------------------------------------------------------------
template<int NV, bool RESID, bool PACKO, int NPROB>
__global__ __launch_bounds__(512, 2)
void mattn_kernel(const float* __restrict__ Q0, const float* __restrict__ Q1,
                  const unsigned int* __restrict__ K0, const unsigned int* __restrict__ K1,
                  const float* __restrict__ VA0, const float* __restrict__ VA1,
                  const float* __restrict__ VB0, const float* __restrict__ VB1,
                  float* __restrict__ OA0, float* __restrict__ OA1,
                  float* __restrict__ OB0, float* __restrict__ OB1,
                  long long q_sb, long long q_sh, int q_sr,
                  long long k_sb, long long k_sh, int k_sr,
                  long long v_sb, long long v_sh, int v_sr,
                  long long o_sb, long long o_sh, int o_sr)
{
    __shared__ __align__(16) unsigned short sK[64 * 128];   // hi|lo planes
    __shared__ __align__(16) unsigned short sV0[64 * 64];   // V^T plain bf16
    __shared__ __align__(16) unsigned short sV1[(NV == 2) ? 64 * 64 : 8];
    __shared__ __align__(16) unsigned short sP[128 * 64];   // P plain bf16

    const int t    = threadIdx.x;
    const int w    = t >> 6;        // wave 0..7
    const int lane = t & 63;
    const int n16  = lane & 15;
    const int quad = lane >> 4;

    // XCD-aware decode
    const int bid = blockIdx.x;
    const int c   = bid & 7;
    const int r1  = bid >> 3;
    const int qt  = r1 & 7;
    const int r2  = r1 >> 3;
    const int g   = r2 & 7;
    const int p   = (NPROB == 2) ? (r2 >> 3) : 0;
    const int bh  = 8 * g + c;
    const int b = bh >> 3, h = bh & 7;
    const int i0 = qt * 128;

    const float* Qb        = (NPROB == 2 && p) ? Q1 : Q0;
    const unsigned int* Kb = (NPROB == 2 && p) ? K1 : K0;
    const float* VAb       = (NPROB == 2 && p) ? VA1 : VA0;
    float* OAb             = (NPROB == 2 && p) ? OA1 : OA0;

    const float* Qg        = Qb  + (size_t)b * q_sb + (size_t)h * q_sh;
    const unsigned int* Kg = Kb  + (size_t)b * k_sb + (size_t)h * k_sh;
    const float* V0g       = VAb + (size_t)b * v_sb + (size_t)h * v_sh;
    const float* V1g = (NV == 2) ? (VB0 + (size_t)b * v_sb + (size_t)h * v_sh) : nullptr;
    float* O0g = OAb + (size_t)b * o_sb + (size_t)h * o_sh;
    float* O1g = (NV == 2) ? (OB0 + (size_t)b * o_sb + (size_t)h * o_sh) : nullptr;

    // persistent Q fragments (hi/lo split), rows i0+16w+n16
    short8 Qh[2], Ql[2];
#pragma unroll
    for (int s = 0; s < 2; s++) {
        const float* qp = Qg + (size_t)(i0 + 16 * w + n16) * q_sr + 32 * s + 8 * quad;
        float qv[8];
        float4 q0 = *(const float4*)qp;
        float4 q1 = *(const float4*)(qp + 4);
        qv[0]=q0.x; qv[1]=q0.y; qv[2]=q0.z; qv[3]=q0.w;
        qv[4]=q1.x; qv[5]=q1.y; qv[6]=q1.z; qv[7]=q1.w;
        split8(qv, Qh[s], Ql[s]);
    }

    float m_ = -1e30f, l_ = 0.f;
    f32x4 O0a[4], O1a[(NV == 2) ? 4 : 1];
#pragma unroll
    for (int nt = 0; nt < 4; nt++) O0a[nt] = (f32x4){0.f,0.f,0.f,0.f};
    if constexpr (NV == 2) {
#pragma unroll
        for (int nt = 0; nt < 4; nt++) O1a[nt] = (f32x4){0.f,0.f,0.f,0.f};
    }

    const float scale = 0.125f;
    const int prow = 16 * w + n16;          // 0..127
    const int krow = t >> 3, kfc = t & 7;   // K staging (one pass, 512 thr)
    const int vc = t & 15, vp = t >> 4;     // V staging: d-chunk, j-pair 0..31

    for (int j0 = 0; j0 < N_; j0 += 64) {
        __syncthreads();

        // ---- stage K (packed u32 -> hi/lo planes, byte split only)
        {
            const unsigned int* kp = Kg + (size_t)(j0 + krow) * k_sr + 8 * kfc;
            uint4 va = *(const uint4*)kp;
            uint4 vb = *(const uint4*)(kp + 4);
            uint4 hi, lo;
            hi.x = (va.x >> 16) | (va.y & 0xFFFF0000u);
            hi.y = (va.z >> 16) | (va.w & 0xFFFF0000u);
            hi.z = (vb.x >> 16) | (vb.y & 0xFFFF0000u);
            hi.w = (vb.z >> 16) | (vb.w & 0xFFFF0000u);
            lo.x = (va.x & 0xFFFFu) | (va.y << 16);
            lo.y = (va.z & 0xFFFFu) | (va.w << 16);
            lo.z = (vb.x & 0xFFFFu) | (vb.y << 16);
            lo.w = (vb.z & 0xFFFFu) | (vb.w << 16);
            const int r15 = krow & 15;
            *(uint4*)&sK[krow * 128 + (((kfc    ) ^ r15) << 3)] = hi;
            *(uint4*)&sK[krow * 128 + (((kfc + 8) ^ r15) << 3)] = lo;
        }
        // ---- stage V transposed, plain bf16, j-pair u32 writes
        {
            const int j = 2 * vp;
            const float* a0 = V0g + (size_t)(j0 + j) * v_sr + 4 * vc;
            float4 va = *(const float4*)a0;
            float4 vb = *(const float4*)(a0 + v_sr);
#pragma unroll
            for (int e = 0; e < 4; e++) {
                float fa = (e==0)?va.x:(e==1)?va.y:(e==2)?va.z:va.w;
                float fb = (e==0)?vb.x:(e==1)?vb.y:(e==2)?vb.z:vb.w;
                unsigned int u = (unsigned int)f2b(fa) | ((unsigned int)f2b(fb) << 16);
                const int d = 4 * vc + e;
                const int phys = (vp >> 2) ^ ((d ^ (d >> 2)) & 7);
                *(unsigned int*)&sV0[d * 64 + (phys << 3) + (j & 7)] = u;
            }
            if constexpr (NV == 2) {
                const float* a1 = V1g + (size_t)(j0 + j) * v_sr + 4 * vc;
                float4 wa = *(const float4*)a1;
                float4 wb = *(const float4*)(a1 + v_sr);
#pragma unroll
                for (int e = 0; e < 4; e++) {
                    float fa = (e==0)?wa.x:(e==1)?wa.y:(e==2)?wa.z:wa.w;
                    float fb = (e==0)?wb.x:(e==1)?wb.y:(e==2)?wb.z:wb.w;
                    unsigned int u = (unsigned int)f2b(fa) | ((unsigned int)f2b(fb) << 16);
                    const int d = 4 * vc + e;
                    const int phys = (vp >> 2) ^ ((d ^ (d >> 2)) & 7);
                    *(unsigned int*)&sV1[d * 64 + (phys << 3) + (j & 7)] = u;
                }
            }
        }
        __syncthreads();

        // ---- S^T = K.Q^T, split 3-MFMA, frags straight from planes
        f32x4 accS[4];
#pragma unroll
        for (int mt = 0; mt < 4; mt++) accS[mt] = (f32x4){0.f,0.f,0.f,0.f};
#pragma unroll
        for (int s = 0; s < 2; s++) {
#pragma unroll
            for (int mt = 0; mt < 4; mt++) {
                const unsigned short* kb2 = &sK[(16 * mt + n16) * 128];
                short8 kh = *(const short8*)&kb2[(((4*s + quad)    ) ^ n16) << 3];
                short8 kl = *(const short8*)&kb2[(((4*s + quad) + 8) ^ n16) << 3];
                accS[mt] = MFMA_BF16(kl, Qh[s], accS[mt], 0, 0, 0);
                accS[mt] = MFMA_BF16(kh, Ql[s], accS[mt], 0, 0, 0);
                accS[mt] = MFMA_BF16(kh, Qh[s], accS[mt], 0, 0, 0);
            }
        }

        // ---- online softmax; P written bf16, wave-local (no barrier)
        float tmax = -1e30f;
#pragma unroll
        for (int mt = 0; mt < 4; mt++)
#pragma unroll
            for (int r = 0; r < 4; r++) tmax = fmaxf(tmax, accS[mt][r]);
        tmax *= scale;
        tmax = fmaxf(tmax, __shfl_xor(tmax, 16));
        tmax = fmaxf(tmax, __shfl_xor(tmax, 32));
        const float mnew = fmaxf(m_, tmax);
        const float alpha = __expf(m_ - mnew);
        m_ = mnew;
        float rsum = 0.f;
#pragma unroll
        for (int mt = 0; mt < 4; mt++) {
            float p0 = __expf(accS[mt][0] * scale - mnew);
            float p1 = __expf(accS[mt][1] * scale - mnew);
            float p2 = __expf(accS[mt][2] * scale - mnew);
            float p3 = __expf(accS[mt][3] * scale - mnew);
            rsum += (p0 + p1) + (p2 + p3);
            uint2 u;
            u.x = (unsigned int)f2b(p0) | ((unsigned int)f2b(p1) << 16);
            u.y = (unsigned int)f2b(p2) | ((unsigned int)f2b(p3) << 16);
            const int phys = (2 * mt + (quad >> 1)) ^ (n16 & 7);
            *(uint2*)&sP[prow * 64 + (phys << 3) + 4 * (quad & 1)] = u;
        }
        rsum += __shfl_xor(rsum, 16);
        rsum += __shfl_xor(rsum, 32);
        l_ = l_ * alpha + rsum;

        float ar[4];
#pragma unroll
        for (int r = 0; r < 4; r++) ar[r] = __shfl(alpha, (quad << 2) + r);
#pragma unroll
        for (int nt = 0; nt < 4; nt++) {
#pragma unroll
            for (int r = 0; r < 4; r++) O0a[nt][r] *= ar[r];
            if constexpr (NV == 2)
#pragma unroll
                for (int r = 0; r < 4; r++) O1a[nt][r] *= ar[r];
        }

        // ---- PV: plain bf16, 1 MFMA per fragment
#pragma unroll
        for (int s = 0; s < 2; s++) {
            short8 Pf = *(const short8*)&sP[prow * 64 + (((4*s + quad) ^ (n16 & 7)) << 3)];
#pragma unroll
            for (int nt = 0; nt < 4; nt++) {
                const int d = 16 * nt + n16;
                const int phys = (4*s + quad) ^ ((d ^ (d >> 2)) & 7);
                short8 vf = *(const short8*)&sV0[d * 64 + (phys << 3)];
                O0a[nt] = MFMA_BF16(Pf, vf, O0a[nt], 0, 0, 0);
                if constexpr (NV == 2) {
                    short8 vf1 = *(const short8*)&sV1[d * 64 + (phys << 3)];
                    O1a[nt] = MFMA_BF16(Pf, vf1, O1a[nt], 0, 0, 0);
                }
            }
        }
    }

    // ---- epilogue
    float linv[4];
#pragma unroll
    for (int r = 0; r < 4; r++) linv[r] = 1.0f / __shfl(l_, (quad << 2) + r);
#pragma unroll
    for (int r = 0; r < 4; r++) {
        const int row = i0 + 16 * w + 4 * quad + r;
#pragma unroll
        for (int nt = 0; nt < 4; nt++) {
            const int col = 16 * nt + n16;
            float v = O0a[nt][r] * linv[r];
            if constexpr (RESID) v += V0g[(size_t)row * v_sr + col];
            if constexpr (PACKO)
                ((unsigned int*)O0g)[(size_t)row * o_sr + col] = packsplit(v);
            else
                O0g[(size_t)row * o_sr + col] = v;
            if constexpr (NV == 2) {
                float v1 = O1a[nt][r] * linv[r];
                if constexpr (RESID) v1 += V1g[(size_t)row * v_sr + col];
                if constexpr (PACKO)
                    ((unsigned int*)O1g)[(size_t)row * o_sr + col] = packsplit(v1);
                else
                    O1g[(size_t)row * o_sr + col] = v1;
            }
        }
    }
}

// ---------------------------------------------------------------------------
extern "C" void kernel_launch(void* const* d_in, const int* in_sizes, int n_in,
                              void* d_out, int out_size, void* d_ws, size_t ws_size,
                              hipStream_t stream)
{
    const float* x1    = (const float*)d_in[0];
    const float* x2    = (const float*)d_in[1];
    const float* Wqkv1 = (const float*)d_in[2];
    const float* Wqkv2 = (const float*)d_in[3];
    const float* Wout1 = (const float*)d_in[4];
    const float* bout1 = (const float*)d_in[5];
    const float* Wout2 = (const float*)d_in[6];
    const float* bout2 = (const float*)d_in[7];
    const float* convw = (const float*)d_in[8];
    const float* convb = (const float*)d_in[9];

    const size_t QKV_ELEMS = (size_t)M_ * QKVC;
    const size_t BND_ELEMS = (size_t)M_ * INNER_;
    if (ws_size < (2 * QKV_ELEMS + 5 * BND_ELEMS) * sizeof(float)) return;

    float* ws   = (float*)d_ws;
    float* qkv1 = ws;
    float* qkv2 = qkv1 + QKV_ELEMS;
    float* MSg  = qkv2 + QKV_ELEMS;
    float* u1   = MSg + BND_ELEMS;
    float* u2   = u1 + BND_ELEMS;
    float* t1m  = u2 + BND_ELEMS;
    float* t2m  = t1m + BND_ELEMS;

    // Aliased packed buffers (time-disjoint):
    unsigned int* x1p   = (unsigned int*)t1m;     // consumed step 1
    unsigned int* x2p   = (unsigned int*)t2m;     // consumed step 1
    unsigned int* MSgp  = (unsigned int*)t1m;     // written step 2, read step 3
    unsigned int* w1pt  = (unsigned int*)u2;      // consumed step 1
    unsigned int* w2pt  = w1pt + (size_t)QKVC * DIM_;
    unsigned int* wo1pt = (unsigned int*)u1;      // packed after u1's last read
    unsigned int* wo2pt = wo1pt + (size_t)DIM_ * DIM_;

    dim3 blk(256);

    // 0) pack activations + qkv weights
    pack_f32<<<dim3(M_ * DIM_ / 1024), blk, 0, stream>>>(x1, x1p);
    pack_f32<<<dim3(M_ * DIM_ / 1024), blk, 0, stream>>>(x2, x2p);
    pack_wt<<<dim3(QKVC / 256, DIM_ / 4), blk, 0, stream>>>(Wqkv1, w1pt, QKVC);
    pack_wt<<<dim3(QKVC / 256, DIM_ / 4), blk, 0, stream>>>(Wqkv2, w2pt, QKVC);

    // 1) QKV projections (MFMA); k-slice cols [512,1024) written packed in place
    gemm_mfma<false, true><<<dim3(QKVC / 128, M_ / 128), blk, 0, stream>>>(
        x1p, w1pt, nullptr, qkv1, M_, QKVC);
    gemm_mfma<false, true><<<dim3(QKVC / 128, M_ / 128), blk, 0, stream>>>(
        x2p, w2pt, nullptr, qkv2, M_, QKVC);

    // 2) conv + sigmoid gate -> MSg (f32) + MSgp (packed)
    convgate_kernel<<<dim3(M_), dim3(128), 0, stream>>>(qkv1, qkv2, convw, convb, MSg, MSgp);

    // Stride descriptors
    const long long msg_sb = (long long)N_ * INNER_, msg_sh = HD_;
    const int       msg_sr = INNER_;
    const long long qkv_sb = (long long)N_ * QKVC, qkv_sh = HD_;
    const int       qkv_sr = QKVC;
    const long long u_sb = (long long)H_ * N_ * HD_, u_sh = (long long)N_ * HD_;
    const int       u_sr = HD_;

    // 3) Attention A: K = MSgp, Q = MSg, V = v-slices, +resid -> u1,u2
    mattn_kernel<2, true, false, 1><<<dim3(512), dim3(512), 0, stream>>>(
        MSg, nullptr, MSgp, nullptr,
        qkv1 + 2 * INNER_, nullptr, qkv2 + 2 * INNER_, nullptr,
        u1, nullptr, u2, nullptr,
        msg_sb, msg_sh, msg_sr,
        msg_sb, msg_sh, msg_sr,
        qkv_sb, qkv_sh, qkv_sr,
        u_sb, u_sh, u_sr);

    // 4) Attention B merged pair: K = qkv k-slice packed, V = u, out packed t
    mattn_kernel<1, false, true, 2><<<dim3(1024), dim3(512), 0, stream>>>(
        qkv1, qkv2,
        (const unsigned int*)qkv1 + INNER_, (const unsigned int*)qkv2 + INNER_,
        u1, u2, nullptr, nullptr,
        t1m, t2m, nullptr, nullptr,
        qkv_sb, qkv_sh, qkv_sr,
        qkv_sb, qkv_sh, qkv_sr,
        u_sb, u_sh, u_sr,
        msg_sb, msg_sh, msg_sr);

    // 4.5) pack output weights into u1 (u1's last reader was step 4)
    pack_wt<<<dim3(DIM_ / 256, DIM_ / 4), blk, 0, stream>>>(Wout1, wo1pt, DIM_);
    pack_wt<<<dim3(DIM_ / 256, DIM_ / 4), blk, 0, stream>>>(Wout2, wo2pt, DIM_);

    // 5) Output projections (MFMA, bias, f32 out)
    float* out1 = (float*)d_out;
    float* out2 = out1 + (size_t)M_ * DIM_;
    gemm_mfma<true, false><<<dim3(DIM_ / 128, M_ / 128), blk, 0, stream>>>(
        (const unsigned int*)t1m, wo1pt, bout1, out1, M_, DIM_);
    gemm_mfma<true, false><<<dim3(DIM_ / 128, M_ / 128), blk, 0, stream>>>(
        (const unsigned int*)t2m, wo2pt, bout2, out2, M_, DIM_);
}